// Round 1
// baseline (3050.601 us; speedup 1.0000x reference)
//
#include <hip/hip_runtime.h>
#include <stdint.h>

typedef __bf16 bf16;
typedef __bf16 bf16x8 __attribute__((ext_vector_type(8)));
typedef float  f32x4  __attribute__((ext_vector_type(4)));

#define LRELU_S 0.2f

__device__ __forceinline__ float lrelu(float v){ return v > 0.f ? v : LRELU_S * v; }
__device__ __forceinline__ float eluf(float v){ return v > 0.f ? v : expm1f(v); }

// ---------------- CSR build ----------------
__global__ void k_count(const int* __restrict__ adj, const int* __restrict__ selfe,
                        unsigned* __restrict__ cnt1, unsigned* __restrict__ cnt2, int E, int EN){
  int i = blockIdx.x * blockDim.x + threadIdx.x;
  if (i < E)  atomicAdd(&cnt1[adj[i]], 1u);
  if (i < EN) atomicAdd(&cnt2[selfe[i]], 1u);
}

// single-block exclusive scan over n counts -> rp[0..n]; zeroes cnt for reuse as cursor
__global__ void k_scan(unsigned* __restrict__ cnt, unsigned* __restrict__ rp, int n){
  __shared__ unsigned s[1024];
  int t = threadIdx.x;
  int chunk = (n + 1023) >> 10;
  int lo = t * chunk, hi = lo + chunk;
  if (lo > n) lo = n;
  if (hi > n) hi = n;
  unsigned sum = 0;
  for (int i = lo; i < hi; i++) sum += cnt[i];
  s[t] = sum; __syncthreads();
  for (int d = 1; d < 1024; d <<= 1){
    unsigned add = (t >= d) ? s[t - d] : 0u;
    __syncthreads();
    s[t] += add;
    __syncthreads();
  }
  unsigned run = s[t] - sum;   // exclusive prefix
  for (int i = lo; i < hi; i++){ rp[i] = run; run += cnt[i]; cnt[i] = 0u; }
  if (hi == n) rp[n] = run;    // total (benign multi-write of same value)
}

__global__ void k_fill(const int* __restrict__ adj, const int* __restrict__ selfe,
                       const float* __restrict__ avals,
                       const unsigned* __restrict__ rp1, const unsigned* __restrict__ rp2,
                       unsigned* __restrict__ cur1, unsigned* __restrict__ cur2,
                       int* __restrict__ cols1, float* __restrict__ vals1,
                       int* __restrict__ dst2, int E, int EN){
  int i = blockIdx.x * blockDim.x + threadIdx.x;
  if (i < E){
    int r = adj[i];
    unsigned slot = rp1[r] + atomicAdd(&cur1[r], 1u);
    cols1[slot] = adj[E + i];
    vals1[slot] = avals[i];
  }
  if (i < EN){
    int sN = selfe[i];
    unsigned slot = rp2[sN] + atomicAdd(&cur2[sN], 1u);
    dst2[slot] = selfe[EN + i];
  }
}

// ---------------- conversions ----------------
__global__ void k_cvt_x(const float* __restrict__ x, bf16* __restrict__ xb, int n8){
  int i = blockIdx.x * blockDim.x + threadIdx.x;
  if (i >= n8) return;
  const f32x4* p = (const f32x4*)(x + (size_t)i * 8);
  f32x4 a = p[0], b = p[1];
  bf16x8 o;
  o[0]=(bf16)a[0]; o[1]=(bf16)a[1]; o[2]=(bf16)a[2]; o[3]=(bf16)a[3];
  o[4]=(bf16)b[0]; o[5]=(bf16)b[1]; o[6]=(bf16)b[2]; o[7]=(bf16)b[3];
  *(bf16x8*)(xb + (size_t)i * 8) = o;
}

// Wt[c][k] = W[k][c], W = [[wg1, wb1],[wg2, wb2]] (cols 0..511 gamma, 512..1023 beta)
__global__ void k_build_wt(const float* __restrict__ wg1, const float* __restrict__ wg2,
                           const float* __restrict__ wb1, const float* __restrict__ wb2,
                           bf16* __restrict__ Wt){
  int i = blockIdx.x * blockDim.x + threadIdx.x;   // 1M threads
  int c = i >> 10, k = i & 1023;
  float v;
  if (c < 512) v = (k < 512) ? wg1[k * 512 + c] : wg2[(k - 512) * 512 + c];
  else { int cc = c - 512; v = (k < 512) ? wb1[k * 512 + cc] : wb2[(k - 512) * 512 + cc]; }
  Wt[(size_t)c * 1024 + k] = (bf16)v;
}

// ---------------- spmm layer 1: wave per row, 8 feats/lane ----------------
__global__ __launch_bounds__(256) void k_spmm1(const unsigned* __restrict__ rp, const int* __restrict__ cols,
    const float* __restrict__ vals, const bf16* __restrict__ xb, bf16* __restrict__ nbb, int N){
  int lane = threadIdx.x & 63;
  int r = blockIdx.x * 4 + (threadIdx.x >> 6);
  if (r >= N) return;
  unsigned b0 = rp[r], b1 = rp[r + 1];
  float acc[8] = {0.f,0.f,0.f,0.f,0.f,0.f,0.f,0.f};
  for (unsigned e = b0; e < b1; ++e){
    int c = cols[e]; float v = vals[e];
    bf16x8 xv = *(const bf16x8*)(xb + (size_t)c * 512 + lane * 8);
    #pragma unroll
    for (int j = 0; j < 8; j++) acc[j] += v * (float)xv[j];
  }
  bf16x8 o;
  #pragma unroll
  for (int j = 0; j < 8; j++) o[j] = (bf16)acc[j];
  *(bf16x8*)(nbb + (size_t)r * 512 + lane * 8) = o;
}

// ---------------- GEMM: [x|nb] (Mx1024) @ Wt^T -> lrelu -> gb bf16 (Mx1024) ----------------
__global__ __launch_bounds__(256) void k_gemm1(const bf16* __restrict__ xb, const bf16* __restrict__ nbb,
    const bf16* __restrict__ Wt, bf16* __restrict__ gbb, int M){
  __shared__ __align__(16) bf16 As[128 * 32];
  __shared__ __align__(16) bf16 Bs[128 * 32];
  int bid = blockIdx.x;
  int rowTiles = gridDim.x >> 3;
  int tile = (bid & 7) * rowTiles + (bid >> 3);       // XCD-chunked swizzle (nwg%8==0)
  int rowBase = (tile >> 3) * 128;
  int colBase = (tile & 7) * 128;
  int tid = threadIdx.x, wave = tid >> 6, lane = tid & 63;
  int wm = wave >> 1, wn = wave & 1;
  f32x4 acc[4][4];
  #pragma unroll
  for (int m = 0; m < 4; m++)
    #pragma unroll
    for (int n = 0; n < 4; n++) acc[m][n] = (f32x4){0.f,0.f,0.f,0.f};

  int sRow = wave * 16 + (lane >> 2);
  int sCol = (lane & 3) * 8;

  for (int kt = 0; kt < 32; ++kt){
    const bf16* Abase = (kt < 16) ? xb : nbb;
    int kcol = (kt & 15) * 32;
    #pragma unroll
    for (int c = 0; c < 2; c++){
      int rr = c * 64 + sRow;
      int grow = rowBase + rr; if (grow >= M) grow = M - 1;
      const bf16* asrc = Abase + (size_t)grow * 512 + kcol + sCol;
      __builtin_amdgcn_global_load_lds((const __attribute__((address_space(1))) void*)asrc,
          (__attribute__((address_space(3))) void*)&As[(size_t)(c * 64 + wave * 16) * 32], 16, 0, 0);
      const bf16* bsrc = Wt + (size_t)(colBase + rr) * 1024 + kt * 32 + sCol;
      __builtin_amdgcn_global_load_lds((const __attribute__((address_space(1))) void*)bsrc,
          (__attribute__((address_space(3))) void*)&Bs[(size_t)(c * 64 + wave * 16) * 32], 16, 0, 0);
    }
    __syncthreads();
    bf16x8 af[4], bfr[4];
    #pragma unroll
    for (int m = 0; m < 4; m++)
      af[m] = *(const bf16x8*)&As[(wm * 64 + m * 16 + (lane & 15)) * 32 + (lane >> 4) * 8];
    #pragma unroll
    for (int n = 0; n < 4; n++)
      bfr[n] = *(const bf16x8*)&Bs[(wn * 64 + n * 16 + (lane & 15)) * 32 + (lane >> 4) * 8];
    #pragma unroll
    for (int m = 0; m < 4; m++)
      #pragma unroll
      for (int n = 0; n < 4; n++)
        acc[m][n] = __builtin_amdgcn_mfma_f32_16x16x32_bf16(af[m], bfr[n], acc[m][n], 0, 0, 0);
    __syncthreads();
  }
  #pragma unroll
  for (int m = 0; m < 4; m++)
    #pragma unroll
    for (int n = 0; n < 4; n++)
      #pragma unroll
      for (int j = 0; j < 4; j++){
        int row = rowBase + wm * 64 + m * 16 + (lane >> 4) * 4 + j;
        int col = colBase + wn * 64 + n * 16 + (lane & 15);
        if (row < M){
          float v = acc[m][n][j];
          v = v > 0.f ? v : LRELU_S * v;     // store lrelu'd pre-activation
          gbb[(size_t)row * 1024 + col] = (bf16)v;
        }
      }
}

// ---------------- relation1 + 24-col projection + attn coeffs: wave per row ----------------
__global__ __launch_bounds__(256) void k_rel1(const float* __restrict__ x, const bf16* __restrict__ nbb,
    const bf16* __restrict__ gbb, const float* __restrict__ r1, const float* __restrict__ g1W,
    const float* __restrict__ g1a, const int* __restrict__ headp,
    float* __restrict__ h1, float* __restrict__ a1s, float* __restrict__ a1d,
    float* __restrict__ nrm1, int N){
  int lane = threadIdx.x & 63;
  int r = blockIdx.x * 4 + (threadIdx.x >> 6);
  if (r >= N) return;
  int head = *headp;
  const float* xr = x + (size_t)r * 512 + lane * 8;
  f32x4 xa = *(const f32x4*)xr, xc = *(const f32x4*)(xr + 4);
  bf16x8 nv = *(const bf16x8*)(nbb + (size_t)r * 512 + lane * 8);
  bf16x8 gv = *(const bf16x8*)(gbb + (size_t)r * 1024 + lane * 8);
  bf16x8 bv = *(const bf16x8*)(gbb + (size_t)r * 1024 + 512 + lane * 8);
  f32x4 ra = *(const f32x4*)(r1 + lane * 8), rb = *(const f32x4*)(r1 + lane * 8 + 4);
  float hacc[24];
  #pragma unroll
  for (int c = 0; c < 24; c++) hacc[c] = 0.f;
  float nrm = 0.f;
  #pragma unroll
  for (int j = 0; j < 8; j++){
    float xf = (j < 4) ? xa[j] : xc[j - 4];
    float rf = (j < 4) ? ra[j] : rb[j - 4];
    float nf = (float)nv[j];
    float g  = (float)gv[j];
    float b  = (float)bv[j];
    float m  = xf + (g + 1.f) * rf + b - nf;   // gamma = lrelu(.)+1, lrelu already applied
    nrm += m * m;
    float hin = head ? xf : (xf + m);
    int f = lane * 8 + j;
    #pragma unroll
    for (int h = 0; h < 3; h++){
      const f32x4* wp = (const f32x4*)(g1W + h * 4096 + f * 8);
      f32x4 w0 = wp[0], w1 = wp[1];
      hacc[h*8+0] += hin * w0[0]; hacc[h*8+1] += hin * w0[1];
      hacc[h*8+2] += hin * w0[2]; hacc[h*8+3] += hin * w0[3];
      hacc[h*8+4] += hin * w1[0]; hacc[h*8+5] += hin * w1[1];
      hacc[h*8+6] += hin * w1[2]; hacc[h*8+7] += hin * w1[3];
    }
  }
  #pragma unroll
  for (int d = 1; d < 64; d <<= 1) nrm += __shfl_xor(nrm, d);
  #pragma unroll
  for (int c = 0; c < 24; c++){
    float v = hacc[c];
    #pragma unroll
    for (int d = 1; d < 64; d <<= 1) v += __shfl_xor(v, d);
    hacc[c] = v;
  }
  if (lane == 0) nrm1[r] = sqrtf(nrm);
  if (lane < 24){
    float hv = hacc[lane];
    h1[(size_t)r * 24 + lane] = hv;
    int h = lane >> 3, o = lane & 7;
    float ps = hv * g1a[h * 16 + o];
    float pd = hv * g1a[h * 16 + 8 + o];
    #pragma unroll
    for (int d = 1; d < 8; d <<= 1){ ps += __shfl_xor(ps, d); pd += __shfl_xor(pd, d); }
    if (o == 0){ a1s[r * 4 + h] = ps; a1d[r * 4 + h] = pd; }
  }
}

// ---------------- GAT layer 1 aggregation: wave per row ----------------
__global__ __launch_bounds__(256) void k_gat1(const unsigned* __restrict__ rp2, const int* __restrict__ dst2,
    const float* __restrict__ h1, const float* __restrict__ a1s, const float* __restrict__ a1d,
    float* __restrict__ x1, int N){
  int lane = threadIdx.x & 63;
  int r = blockIdx.x * 4 + (threadIdx.x >> 6);
  if (r >= N) return;
  int cl = (lane < 24) ? lane : 0;
  int h = cl >> 3;
  float as = a1s[r * 4 + h];
  unsigned b0 = rp2[r], b1 = rp2[r + 1];
  float hp = 0.f, rs = 0.f;
  for (unsigned e = b0; e < b1; ++e){
    int d = dst2[e];
    float z = as + a1d[d * 4 + h];
    float ee = expf(-lrelu(z));
    hp += ee * h1[(size_t)d * 24 + cl];
    rs += ee;
  }
  if (lane < 24){
    float v = hp / rs;
    v = eluf(v); v = eluf(v);   // elu in _gat_head, then elu after concat
    x1[(size_t)r * 24 + lane] = v;
  }
}

// ---------------- spmm layer 2: wave per row, 24 lanes ----------------
__global__ __launch_bounds__(256) void k_spmm2(const unsigned* __restrict__ rp, const int* __restrict__ cols,
    const float* __restrict__ vals, const float* __restrict__ x1, float* __restrict__ nb2, int N){
  int lane = threadIdx.x & 63;
  int r = blockIdx.x * 4 + (threadIdx.x >> 6);
  if (r >= N) return;
  int cl = (lane < 24) ? lane : 0;
  unsigned b0 = rp[r], b1 = rp[r + 1];
  float acc = 0.f;
  for (unsigned e = b0; e < b1; ++e)
    acc += vals[e] * x1[(size_t)cols[e] * 24 + cl];
  if (lane < 24) nb2[(size_t)r * 24 + lane] = acc;
}

// ---------------- relation2 + gat2_W projection + attn coeffs: thread per row ----------------
__global__ void k_rel2(const float* __restrict__ x1, const float* __restrict__ nb2,
    const float* __restrict__ wg1, const float* __restrict__ wg2,
    const float* __restrict__ wb1, const float* __restrict__ wb2,
    const float* __restrict__ r2, const float* __restrict__ W2, const float* __restrict__ a2,
    const int* __restrict__ headp,
    float* __restrict__ hg, float* __restrict__ a2s, float* __restrict__ a2d,
    float* __restrict__ nrm2, int N){
  int r = blockIdx.x * blockDim.x + threadIdx.x;
  if (r >= N) return;
  int head = *headp;
  float xr[24], nr[24], hin[24];
  #pragma unroll
  for (int i = 0; i < 24; i++){ xr[i] = x1[(size_t)r*24+i]; nr[i] = nb2[(size_t)r*24+i]; }
  float nrm = 0.f;
  #pragma unroll
  for (int j = 0; j < 24; j++){
    float gp = 0.f, bp = 0.f;
    #pragma unroll
    for (int i = 0; i < 24; i++){
      gp += xr[i] * wg1[i*24+j] + nr[i] * wg2[i*24+j];
      bp += xr[i] * wb1[i*24+j] + nr[i] * wb2[i*24+j];
    }
    float m = xr[j] + (lrelu(gp) + 1.f) * r2[j] + lrelu(bp) - nr[j];
    nrm += m * m;
    hin[j] = head ? xr[j] : (xr[j] + m);
  }
  nrm2[r] = sqrtf(nrm);
  float as = 0.f, ad = 0.f;
  #pragma unroll
  for (int c = 0; c < 32; c++){
    float v = 0.f;
    #pragma unroll
    for (int i = 0; i < 24; i++) v += hin[i] * W2[i*32+c];
    hg[(size_t)r*32 + c] = v;
    as += v * a2[c]; ad += v * a2[32 + c];
  }
  a2s[r] = as; a2d[r] = ad;
}

// ---------------- GAT layer 2 aggregation -> d_out ----------------
__global__ __launch_bounds__(256) void k_gat2(const unsigned* __restrict__ rp2, const int* __restrict__ dst2,
    const float* __restrict__ hg, const float* __restrict__ a2s, const float* __restrict__ a2d,
    float* __restrict__ out, int N){
  int lane = threadIdx.x & 63;
  int r = blockIdx.x * 4 + (threadIdx.x >> 6);
  if (r >= N) return;
  int cl = lane & 31;
  float as = a2s[r];
  unsigned b0 = rp2[r], b1 = rp2[r + 1];
  float hp = 0.f, rs = 0.f;
  for (unsigned e = b0; e < b1; ++e){
    int d = dst2[e];
    float z = as + a2d[d];
    float ee = expf(-lrelu(z));
    hp += ee * hg[(size_t)d * 32 + cl];
    rs += ee;
  }
  if (lane < 32) out[(size_t)r * 32 + lane] = eluf(hp / rs);
}

extern "C" void kernel_launch(void* const* d_in, const int* in_sizes, int n_in,
                              void* d_out, int out_size, void* d_ws, size_t ws_size,
                              hipStream_t stream){
  const float* x     = (const float*)d_in[0];
  const float* avals = (const float*)d_in[1];
  const float* wg1   = (const float*)d_in[2];
  const float* wg2   = (const float*)d_in[3];
  const float* wb1   = (const float*)d_in[4];
  const float* wb2   = (const float*)d_in[5];
  const float* r1    = (const float*)d_in[6];
  const float* g1W   = (const float*)d_in[7];
  const float* g1a   = (const float*)d_in[8];
  const float* w2g1  = (const float*)d_in[9];
  const float* w2g2  = (const float*)d_in[10];
  const float* w2b1  = (const float*)d_in[11];
  const float* w2b2  = (const float*)d_in[12];
  const float* r2    = (const float*)d_in[13];
  const float* W2    = (const float*)d_in[14];
  const float* a2    = (const float*)d_in[15];
  const int*   adj   = (const int*)d_in[16];
  const int*   selfe = (const int*)d_in[17];
  const int*   headp = (const int*)d_in[18];

  const int N  = in_sizes[0] / 512;
  const int E  = in_sizes[1];
  const int EN = in_sizes[17] / 2;

  char* w = (char*)d_ws; size_t off = 0;
  auto carve = [&](size_t bytes) -> char* {
    char* p = w + off; off = (off + bytes + 255) & ~(size_t)255; return p;
  };
  unsigned* rp1   = (unsigned*)carve(((size_t)N + 1) * 4);
  unsigned* rp2   = (unsigned*)carve(((size_t)N + 1) * 4);
  unsigned* cnt1  = (unsigned*)carve(((size_t)N + 1) * 4);
  unsigned* cnt2  = (unsigned*)carve(((size_t)N + 1) * 4);
  int*      cols1 = (int*)carve((size_t)E * 4);
  float*    vals1 = (float*)carve((size_t)E * 4);
  int*      dst2  = (int*)carve((size_t)EN * 4);
  bf16*     xb    = (bf16*)carve((size_t)N * 512 * 2);
  bf16*     nbb   = (bf16*)carve((size_t)N * 512 * 2);
  bf16*     Wt    = (bf16*)carve((size_t)1024 * 1024 * 2);
  bf16*     gbb   = (bf16*)carve((size_t)N * 1024 * 2);
  float*    h1    = (float*)carve((size_t)N * 24 * 4);
  float*    a1s   = (float*)carve((size_t)N * 4 * 4);
  float*    a1d   = (float*)carve((size_t)N * 4 * 4);
  float*    x1    = (float*)carve((size_t)N * 24 * 4);
  float*    nb2   = (float*)carve((size_t)N * 24 * 4);
  float*    hg    = (float*)carve((size_t)N * 32 * 4);
  float*    a2s   = (float*)carve((size_t)N * 4);
  float*    a2d   = (float*)carve((size_t)N * 4);

  float* out  = (float*)d_out;
  float* nrm1 = out + (size_t)N * 32;
  float* nrm2 = nrm1 + N;

  hipMemsetAsync(cnt1, 0, ((size_t)N + 1) * 4, stream);
  hipMemsetAsync(cnt2, 0, ((size_t)N + 1) * 4, stream);

  const int tb = 256;
  k_count<<<(EN + tb - 1) / tb, tb, 0, stream>>>(adj, selfe, cnt1, cnt2, E, EN);
  k_scan<<<1, 1024, 0, stream>>>(cnt1, rp1, N);
  k_scan<<<1, 1024, 0, stream>>>(cnt2, rp2, N);
  k_fill<<<(EN + tb - 1) / tb, tb, 0, stream>>>(adj, selfe, avals, rp1, rp2, cnt1, cnt2,
                                                cols1, vals1, dst2, E, EN);
  int n8 = N * 512 / 8;
  k_cvt_x<<<(n8 + tb - 1) / tb, tb, 0, stream>>>(x, xb, n8);
  k_build_wt<<<(1024 * 1024) / tb, tb, 0, stream>>>(wg1, wg2, wb1, wb2, Wt);

  int rb = (N + 3) / 4;
  k_spmm1<<<rb, 256, 0, stream>>>(rp1, cols1, vals1, xb, nbb, N);

  int rowTiles = (N + 127) / 128;
  k_gemm1<<<rowTiles * 8, 256, 0, stream>>>(xb, nbb, Wt, gbb, N);

  k_rel1<<<rb, 256, 0, stream>>>(x, nbb, gbb, r1, g1W, g1a, headp, h1, a1s, a1d, nrm1, N);
  k_gat1<<<rb, 256, 0, stream>>>(rp2, dst2, h1, a1s, a1d, x1, N);
  k_spmm2<<<rb, 256, 0, stream>>>(rp1, cols1, vals1, x1, nb2, N);
  k_rel2<<<(N + tb - 1) / tb, tb, 0, stream>>>(x1, nb2, w2g1, w2g2, w2b1, w2b2, r2, W2, a2,
                                               headp, hg, a2s, a2d, nrm2, N);
  k_gat2<<<rb, 256, 0, stream>>>(rp2, dst2, hg, a2s, a2d, out, N);
}

// Round 3
// 2767.472 us; speedup vs baseline: 1.1023x; 1.1023x over previous
//
#include <hip/hip_runtime.h>
#include <stdint.h>

typedef __bf16 bf16;
typedef __bf16 bf16x8 __attribute__((ext_vector_type(8)));
typedef float  f32x4  __attribute__((ext_vector_type(4)));

#define LRELU_S 0.2f

__device__ __forceinline__ float lrelu(float v){ return v > 0.f ? v : LRELU_S * v; }
__device__ __forceinline__ float eluf(float v){ return v > 0.f ? v : expm1f(v); }

// ---------------- CSR build ----------------
__global__ void k_count(const int* __restrict__ adj, const int* __restrict__ selfe,
                        unsigned* __restrict__ cnt1, unsigned* __restrict__ cnt2, int E, int EN){
  int i = blockIdx.x * blockDim.x + threadIdx.x;
  if (i < E)  atomicAdd(&cnt1[adj[i]], 1u);
  if (i < EN) atomicAdd(&cnt2[selfe[i]], 1u);
}

__global__ void k_scan(unsigned* __restrict__ cnt, unsigned* __restrict__ rp, int n){
  __shared__ unsigned s[1024];
  int t = threadIdx.x;
  int chunk = (n + 1023) >> 10;
  int lo = t * chunk, hi = lo + chunk;
  if (lo > n) lo = n;
  if (hi > n) hi = n;
  unsigned sum = 0;
  for (int i = lo; i < hi; i++) sum += cnt[i];
  s[t] = sum; __syncthreads();
  for (int d = 1; d < 1024; d <<= 1){
    unsigned add = (t >= d) ? s[t - d] : 0u;
    __syncthreads();
    s[t] += add;
    __syncthreads();
  }
  unsigned run = s[t] - sum;
  for (int i = lo; i < hi; i++){ rp[i] = run; run += cnt[i]; cnt[i] = 0u; }
  if (hi == n) rp[n] = run;
}

__global__ void k_fill(const int* __restrict__ adj, const int* __restrict__ selfe,
                       const float* __restrict__ avals,
                       const unsigned* __restrict__ rp1, const unsigned* __restrict__ rp2,
                       unsigned* __restrict__ cur1, unsigned* __restrict__ cur2,
                       int* __restrict__ cols1, float* __restrict__ vals1,
                       int* __restrict__ dst2, int E, int EN){
  int i = blockIdx.x * blockDim.x + threadIdx.x;
  if (i < E){
    int r = adj[i];
    unsigned slot = rp1[r] + atomicAdd(&cur1[r], 1u);
    cols1[slot] = adj[E + i];
    vals1[slot] = avals[i];
  }
  if (i < EN){
    int sN = selfe[i];
    unsigned slot = rp2[sN] + atomicAdd(&cur2[sN], 1u);
    dst2[slot] = selfe[EN + i];
  }
}

// ---------------- conversions / packing ----------------
__global__ void k_cvt_x(const float* __restrict__ x, bf16* __restrict__ xb, int n8){
  int i = blockIdx.x * blockDim.x + threadIdx.x;
  if (i >= n8) return;
  const f32x4* p = (const f32x4*)(x + (size_t)i * 8);
  f32x4 a = p[0], b = p[1];
  bf16x8 o;
  o[0]=(bf16)a[0]; o[1]=(bf16)a[1]; o[2]=(bf16)a[2]; o[3]=(bf16)a[3];
  o[4]=(bf16)b[0]; o[5]=(bf16)b[1]; o[6]=(bf16)b[2]; o[7]=(bf16)b[3];
  *(bf16x8*)(xb + (size_t)i * 8) = o;
}

// Wt[c][k] = W[k][c], W = [[wg1, wb1],[wg2, wb2]] (cols 0..511 gamma, 512..1023 beta)
__global__ void k_build_wt(const float* __restrict__ wg1, const float* __restrict__ wg2,
                           const float* __restrict__ wb1, const float* __restrict__ wb2,
                           bf16* __restrict__ Wt){
  int i = blockIdx.x * blockDim.x + threadIdx.x;
  int c = i >> 10, k = i & 1023;
  float v;
  if (c < 512) v = (k < 512) ? wg1[k * 512 + c] : wg2[(k - 512) * 512 + c];
  else { int cc = c - 512; v = (k < 512) ? wb1[k * 512 + cc] : wb2[(k - 512) * 512 + cc]; }
  Wt[(size_t)c * 1024 + k] = (bf16)v;
}

// g1Wb[c][k] (bf16, c in 0..31): c = h*8+o -> g1W[h][k][o]; c>=24 -> 0
__global__ void k_build_w1b(const float* __restrict__ g1W, bf16* __restrict__ g1Wb){
  int i = blockIdx.x * blockDim.x + threadIdx.x;   // 32*512
  if (i >= 32 * 512) return;
  int c = i >> 9, k = i & 511;
  float v = 0.f;
  if (c < 24){ int h = c >> 3, o = c & 7; v = g1W[h * 4096 + k * 8 + o]; }
  g1Wb[i] = (bf16)v;
}

// ---------------- spmm layer 1: wave per row, 8 feats/lane ----------------
__global__ __launch_bounds__(256) void k_spmm1(const unsigned* __restrict__ rp, const int* __restrict__ cols,
    const float* __restrict__ vals, const bf16* __restrict__ xb, bf16* __restrict__ nbb, int N){
  int lane = threadIdx.x & 63;
  int r = blockIdx.x * 4 + (threadIdx.x >> 6);
  if (r >= N) return;
  unsigned b0 = rp[r], b1 = rp[r + 1];
  float acc[8] = {0.f,0.f,0.f,0.f,0.f,0.f,0.f,0.f};
  for (unsigned e = b0; e < b1; ++e){
    int c = cols[e]; float v = vals[e];
    bf16x8 xv = *(const bf16x8*)(xb + (size_t)c * 512 + lane * 8);
    #pragma unroll
    for (int j = 0; j < 8; j++) acc[j] += v * (float)xv[j];
  }
  bf16x8 o;
  #pragma unroll
  for (int j = 0; j < 8; j++) o[j] = (bf16)acc[j];
  *(bf16x8*)(nbb + (size_t)r * 512 + lane * 8) = o;
}

// ---------------- fused GEMM + relation1 epilogue ----------------
// Block covers 128 rows x 128 features (gamma cols fBase..fBase+127 AND beta cols 512+fBase..).
// Epilogue: m = x + (lrelu(g)+1)*r1 + lrelu(b) - nb; hin -> hinb bf16; atomicAdd(nrmsq[row], m^2)
__global__ __launch_bounds__(256) void k_gemm1f(const bf16* __restrict__ xb, const bf16* __restrict__ nbb,
    const bf16* __restrict__ Wt, const float* __restrict__ r1, const int* __restrict__ headp,
    bf16* __restrict__ hinb, float* __restrict__ nrmsq, int M){
  __shared__ __align__(16) bf16 As[128 * 32];
  __shared__ __align__(16) bf16 Bg[128 * 32];
  __shared__ __align__(16) bf16 Bb[128 * 32];
  int bid = blockIdx.x;
  int chunk = gridDim.x >> 3;                     // nwg % 8 == 0
  int tile = (bid & 7) * chunk + (bid >> 3);      // XCD-chunked swizzle
  int rowBase = (tile >> 2) * 128;
  int fBase = (tile & 3) * 128;
  int tid = threadIdx.x, wave = tid >> 6, lane = tid & 63;
  int wm = wave >> 1, wn = wave & 1;
  f32x4 aG[4][4], aB[4][4];
  #pragma unroll
  for (int m = 0; m < 4; m++)
    #pragma unroll
    for (int n = 0; n < 4; n++){ aG[m][n] = (f32x4){0.f,0.f,0.f,0.f}; aB[m][n] = (f32x4){0.f,0.f,0.f,0.f}; }

  int sRow = wave * 16 + (lane >> 2);
  int sCol = (lane & 3) * 8;

  for (int kt = 0; kt < 32; ++kt){
    const bf16* Abase = (kt < 16) ? xb : nbb;
    int kcol = (kt & 15) * 32;
    #pragma unroll
    for (int c = 0; c < 2; c++){
      int rr = c * 64 + sRow;
      int grow = rowBase + rr; if (grow >= M) grow = M - 1;
      const bf16* asrc = Abase + (size_t)grow * 512 + kcol + sCol;
      __builtin_amdgcn_global_load_lds((const __attribute__((address_space(1))) void*)asrc,
          (__attribute__((address_space(3))) void*)&As[(size_t)(c * 64 + wave * 16) * 32], 16, 0, 0);
      const bf16* gsrc = Wt + (size_t)(fBase + rr) * 1024 + kt * 32 + sCol;
      __builtin_amdgcn_global_load_lds((const __attribute__((address_space(1))) void*)gsrc,
          (__attribute__((address_space(3))) void*)&Bg[(size_t)(c * 64 + wave * 16) * 32], 16, 0, 0);
      const bf16* bsrc = Wt + (size_t)(512 + fBase + rr) * 1024 + kt * 32 + sCol;
      __builtin_amdgcn_global_load_lds((const __attribute__((address_space(1))) void*)bsrc,
          (__attribute__((address_space(3))) void*)&Bb[(size_t)(c * 64 + wave * 16) * 32], 16, 0, 0);
    }
    __syncthreads();
    bf16x8 af[4], bg[4], bb[4];
    #pragma unroll
    for (int m = 0; m < 4; m++)
      af[m] = *(const bf16x8*)&As[(wm * 64 + m * 16 + (lane & 15)) * 32 + (lane >> 4) * 8];
    #pragma unroll
    for (int n = 0; n < 4; n++){
      bg[n] = *(const bf16x8*)&Bg[(wn * 64 + n * 16 + (lane & 15)) * 32 + (lane >> 4) * 8];
      bb[n] = *(const bf16x8*)&Bb[(wn * 64 + n * 16 + (lane & 15)) * 32 + (lane >> 4) * 8];
    }
    #pragma unroll
    for (int m = 0; m < 4; m++)
      #pragma unroll
      for (int n = 0; n < 4; n++){
        aG[m][n] = __builtin_amdgcn_mfma_f32_16x16x32_bf16(af[m], bg[n], aG[m][n], 0, 0, 0);
        aB[m][n] = __builtin_amdgcn_mfma_f32_16x16x32_bf16(af[m], bb[n], aB[m][n], 0, 0, 0);
      }
    __syncthreads();
  }

  int head = *headp;
  float rf[4];
  #pragma unroll
  for (int n = 0; n < 4; n++) rf[n] = r1[fBase + wn * 64 + n * 16 + (lane & 15)];
  #pragma unroll
  for (int m = 0; m < 4; m++){
    #pragma unroll
    for (int j = 0; j < 4; j++){
      int row = rowBase + wm * 64 + m * 16 + (lane >> 4) * 4 + j;
      bool ok = row < M;
      int rowc = ok ? row : M - 1;
      float msq = 0.f;
      #pragma unroll
      for (int n = 0; n < 4; n++){
        int f = fBase + wn * 64 + n * 16 + (lane & 15);
        float g = lrelu(aG[m][n][j]);
        float b = lrelu(aB[m][n][j]);
        float xf = (float)xb[(size_t)rowc * 512 + f];
        float nf = (float)nbb[(size_t)rowc * 512 + f];
        float mv = xf + (g + 1.f) * rf[n] + b - nf;
        msq += mv * mv;
        float hin = head ? xf : (xf + mv);
        if (ok) hinb[(size_t)row * 512 + f] = (bf16)hin;
      }
      #pragma unroll
      for (int d = 1; d < 16; d <<= 1) msq += __shfl_xor(msq, d);
      if (ok && (lane & 15) == 0) atomicAdd(&nrmsq[row], msq);
    }
  }
}

// ---------------- skinny projection GEMM: hinb [N,512] @ g1Wb^T [512,32] -> h1 [N,32] f32 ----
__global__ __launch_bounds__(256) void k_proj1(const bf16* __restrict__ hinb, const bf16* __restrict__ g1Wb,
    float* __restrict__ h1, int N){
  __shared__ __align__(16) bf16 Bs[32 * 520];   // padded stride (2-way banks = free)
  __shared__ __align__(16) bf16 As[256 * 32];
  int tid = threadIdx.x, wave = tid >> 6, lane = tid & 63;
  #pragma unroll
  for (int i = 0; i < 8; i++){
    int e8 = tid + i * 256;
    int c = e8 >> 6, k = (e8 & 63) * 8;
    bf16x8 v = *(const bf16x8*)(g1Wb + c * 512 + k);
    *(bf16x8*)&Bs[c * 520 + k] = v;
  }
  int rBase = blockIdx.x * 256;
  f32x4 acc[4][2];
  #pragma unroll
  for (int m = 0; m < 4; m++){ acc[m][0] = (f32x4){0,0,0,0}; acc[m][1] = (f32x4){0,0,0,0}; }
  __syncthreads();
  for (int kt = 0; kt < 16; ++kt){
    #pragma unroll
    for (int i = 0; i < 4; i++){
      int r = (tid >> 2) + i * 64;
      int grow = rBase + r; if (grow >= N) grow = N - 1;
      const bf16* src = hinb + (size_t)grow * 512 + kt * 32 + (tid & 3) * 8;
      __builtin_amdgcn_global_load_lds((const __attribute__((address_space(1))) void*)src,
          (__attribute__((address_space(3))) void*)&As[(size_t)(i * 64 + wave * 16) * 32], 16, 0, 0);
    }
    __syncthreads();
    bf16x8 bf0 = *(const bf16x8*)&Bs[(0 * 16 + (lane & 15)) * 520 + kt * 32 + (lane >> 4) * 8];
    bf16x8 bf1 = *(const bf16x8*)&Bs[(1 * 16 + (lane & 15)) * 520 + kt * 32 + (lane >> 4) * 8];
    #pragma unroll
    for (int m = 0; m < 4; m++){
      bf16x8 af = *(const bf16x8*)&As[(wave * 64 + m * 16 + (lane & 15)) * 32 + (lane >> 4) * 8];
      acc[m][0] = __builtin_amdgcn_mfma_f32_16x16x32_bf16(af, bf0, acc[m][0], 0, 0, 0);
      acc[m][1] = __builtin_amdgcn_mfma_f32_16x16x32_bf16(af, bf1, acc[m][1], 0, 0, 0);
    }
    __syncthreads();
  }
  #pragma unroll
  for (int m = 0; m < 4; m++)
    #pragma unroll
    for (int n = 0; n < 2; n++)
      #pragma unroll
      for (int j = 0; j < 4; j++){
        int row = rBase + wave * 64 + m * 16 + (lane >> 4) * 4 + j;
        int col = n * 16 + (lane & 15);
        if (row < N) h1[(size_t)row * 32 + col] = acc[m][n][j];
      }
}

// ---------------- attn coeffs + nrm1: wave per row ----------------
__global__ __launch_bounds__(256) void k_att1(const float* __restrict__ h1, const float* __restrict__ g1a,
    const float* __restrict__ nrmsq, float* __restrict__ a1s, float* __restrict__ a1d,
    float* __restrict__ nrm1, int N){
  int lane = threadIdx.x & 63;
  int r = blockIdx.x * 4 + (threadIdx.x >> 6);
  if (r >= N) return;
  if (lane < 24){
    float hv = h1[(size_t)r * 32 + lane];
    int h = lane >> 3, o = lane & 7;
    float ps = hv * g1a[h * 16 + o];
    float pd = hv * g1a[h * 16 + 8 + o];
    #pragma unroll
    for (int d = 1; d < 8; d <<= 1){ ps += __shfl_xor(ps, d); pd += __shfl_xor(pd, d); }
    if (o == 0){ a1s[r * 4 + h] = ps; a1d[r * 4 + h] = pd; }
  } else if (lane == 24){
    nrm1[r] = sqrtf(nrmsq[r]);
  }
}

// ---------------- GAT layer 1 aggregation: wave per row (h1 stride 32) ----------------
__global__ __launch_bounds__(256) void k_gat1(const unsigned* __restrict__ rp2, const int* __restrict__ dst2,
    const float* __restrict__ h1, const float* __restrict__ a1s, const float* __restrict__ a1d,
    float* __restrict__ x1, int N){
  int lane = threadIdx.x & 63;
  int r = blockIdx.x * 4 + (threadIdx.x >> 6);
  if (r >= N) return;
  int cl = (lane < 24) ? lane : 0;
  int h = cl >> 3;
  float as = a1s[r * 4 + h];
  unsigned b0 = rp2[r], b1 = rp2[r + 1];
  float hp = 0.f, rs = 0.f;
  for (unsigned e = b0; e < b1; ++e){
    int d = dst2[e];
    float z = as + a1d[d * 4 + h];
    float ee = expf(-lrelu(z));
    hp += ee * h1[(size_t)d * 32 + cl];
    rs += ee;
  }
  if (lane < 24){
    float v = hp / rs;
    v = eluf(v); v = eluf(v);
    x1[(size_t)r * 24 + lane] = v;
  }
}

// ---------------- spmm layer 2: wave per row, 24 lanes ----------------
__global__ __launch_bounds__(256) void k_spmm2(const unsigned* __restrict__ rp, const int* __restrict__ cols,
    const float* __restrict__ vals, const float* __restrict__ x1, float* __restrict__ nb2, int N){
  int lane = threadIdx.x & 63;
  int r = blockIdx.x * 4 + (threadIdx.x >> 6);
  if (r >= N) return;
  int cl = (lane < 24) ? lane : 0;
  unsigned b0 = rp[r], b1 = rp[r + 1];
  float acc = 0.f;
  for (unsigned e = b0; e < b1; ++e)
    acc += vals[e] * x1[(size_t)cols[e] * 24 + cl];
  if (lane < 24) nb2[(size_t)r * 24 + lane] = acc;
}

// ---------------- relation2 + gat2_W projection + attn coeffs: thread per row ----------------
__global__ void k_rel2(const float* __restrict__ x1, const float* __restrict__ nb2,
    const float* __restrict__ wg1, const float* __restrict__ wg2,
    const float* __restrict__ wb1, const float* __restrict__ wb2,
    const float* __restrict__ r2, const float* __restrict__ W2, const float* __restrict__ a2,
    const int* __restrict__ headp,
    float* __restrict__ hg, float* __restrict__ a2s, float* __restrict__ a2d,
    float* __restrict__ nrm2, int N){
  int r = blockIdx.x * blockDim.x + threadIdx.x;
  if (r >= N) return;
  int head = *headp;
  float xr[24], nr[24], hin[24];
  #pragma unroll
  for (int i = 0; i < 24; i++){ xr[i] = x1[(size_t)r*24+i]; nr[i] = nb2[(size_t)r*24+i]; }
  float nrm = 0.f;
  #pragma unroll
  for (int j = 0; j < 24; j++){
    float gp = 0.f, bp = 0.f;
    #pragma unroll
    for (int i = 0; i < 24; i++){
      gp += xr[i] * wg1[i*24+j] + nr[i] * wg2[i*24+j];
      bp += xr[i] * wb1[i*24+j] + nr[i] * wb2[i*24+j];
    }
    float m = xr[j] + (lrelu(gp) + 1.f) * r2[j] + lrelu(bp) - nr[j];
    nrm += m * m;
    hin[j] = head ? xr[j] : (xr[j] + m);
  }
  nrm2[r] = sqrtf(nrm);
  float as = 0.f, ad = 0.f;
  #pragma unroll
  for (int c = 0; c < 32; c++){
    float v = 0.f;
    #pragma unroll
    for (int i = 0; i < 24; i++) v += hin[i] * W2[i*32+c];
    hg[(size_t)r*32 + c] = v;
    as += v * a2[c]; ad += v * a2[32 + c];
  }
  a2s[r] = as; a2d[r] = ad;
}

// ---------------- GAT layer 2 aggregation -> d_out ----------------
__global__ __launch_bounds__(256) void k_gat2(const unsigned* __restrict__ rp2, const int* __restrict__ dst2,
    const float* __restrict__ hg, const float* __restrict__ a2s, const float* __restrict__ a2d,
    float* __restrict__ out, int N){
  int lane = threadIdx.x & 63;
  int r = blockIdx.x * 4 + (threadIdx.x >> 6);
  if (r >= N) return;
  int cl = lane & 31;
  float as = a2s[r];
  unsigned b0 = rp2[r], b1 = rp2[r + 1];
  float hp = 0.f, rs = 0.f;
  for (unsigned e = b0; e < b1; ++e){
    int d = dst2[e];
    float z = as + a2d[d];
    float ee = expf(-lrelu(z));
    hp += ee * hg[(size_t)d * 32 + cl];
    rs += ee;
  }
  if (lane < 32) out[(size_t)r * 32 + lane] = eluf(hp / rs);
}

extern "C" void kernel_launch(void* const* d_in, const int* in_sizes, int n_in,
                              void* d_out, int out_size, void* d_ws, size_t ws_size,
                              hipStream_t stream){
  const float* x     = (const float*)d_in[0];
  const float* avals = (const float*)d_in[1];
  const float* wg1   = (const float*)d_in[2];
  const float* wg2   = (const float*)d_in[3];
  const float* wb1   = (const float*)d_in[4];
  const float* wb2   = (const float*)d_in[5];
  const float* r1    = (const float*)d_in[6];
  const float* g1W   = (const float*)d_in[7];
  const float* g1a   = (const float*)d_in[8];
  const float* w2g1  = (const float*)d_in[9];
  const float* w2g2  = (const float*)d_in[10];
  const float* w2b1  = (const float*)d_in[11];
  const float* w2b2  = (const float*)d_in[12];
  const float* r2    = (const float*)d_in[13];
  const float* W2    = (const float*)d_in[14];
  const float* a2    = (const float*)d_in[15];
  const int*   adj   = (const int*)d_in[16];
  const int*   selfe = (const int*)d_in[17];
  const int*   headp = (const int*)d_in[18];

  const int N  = in_sizes[0] / 512;
  const int E  = in_sizes[1];
  const int EN = in_sizes[17] / 2;

  char* w = (char*)d_ws; size_t off = 0;
  auto carve = [&](size_t bytes) -> char* {
    char* p = w + off; off = (off + bytes + 255) & ~(size_t)255; return p;
  };
  unsigned* rp1   = (unsigned*)carve(((size_t)N + 1) * 4);
  unsigned* rp2   = (unsigned*)carve(((size_t)N + 1) * 4);
  unsigned* cnt1  = (unsigned*)carve(((size_t)N + 1) * 4);
  unsigned* cnt2  = (unsigned*)carve(((size_t)N + 1) * 4);
  int*      cols1 = (int*)carve((size_t)E * 4);
  float*    vals1 = (float*)carve((size_t)E * 4);
  int*      dst2  = (int*)carve((size_t)EN * 4);
  bf16*     xb    = (bf16*)carve((size_t)N * 512 * 2);
  bf16*     nbb   = (bf16*)carve((size_t)N * 512 * 2);
  bf16*     Wt    = (bf16*)carve((size_t)1024 * 1024 * 2);
  bf16*     g1Wb  = (bf16*)carve((size_t)32 * 512 * 2);
  bf16*     hinb  = (bf16*)carve((size_t)N * 512 * 2);
  float*    nrmsq = (float*)carve((size_t)N * 4);
  float*    h1    = (float*)carve((size_t)N * 32 * 4);
  float*    a1s   = (float*)carve((size_t)N * 4 * 4);
  float*    a1d   = (float*)carve((size_t)N * 4 * 4);
  float*    x1    = (float*)carve((size_t)N * 24 * 4);
  float*    nb2   = (float*)carve((size_t)N * 24 * 4);
  float*    hg    = (float*)carve((size_t)N * 32 * 4);
  float*    a2s   = (float*)carve((size_t)N * 4);
  float*    a2d   = (float*)carve((size_t)N * 4);

  float* out  = (float*)d_out;
  float* nrm1 = out + (size_t)N * 32;
  float* nrm2 = nrm1 + N;

  hipMemsetAsync(cnt1, 0, ((size_t)N + 1) * 4, stream);
  hipMemsetAsync(cnt2, 0, ((size_t)N + 1) * 4, stream);
  hipMemsetAsync(nrmsq, 0, (size_t)N * 4, stream);

  const int tb = 256;
  k_count<<<(EN + tb - 1) / tb, tb, 0, stream>>>(adj, selfe, cnt1, cnt2, E, EN);
  k_scan<<<1, 1024, 0, stream>>>(cnt1, rp1, N);
  k_scan<<<1, 1024, 0, stream>>>(cnt2, rp2, N);
  k_fill<<<(EN + tb - 1) / tb, tb, 0, stream>>>(adj, selfe, avals, rp1, rp2, cnt1, cnt2,
                                                cols1, vals1, dst2, E, EN);
  int n8 = N * 512 / 8;
  k_cvt_x<<<(n8 + tb - 1) / tb, tb, 0, stream>>>(x, xb, n8);
  k_build_wt<<<(1024 * 1024) / tb, tb, 0, stream>>>(wg1, wg2, wb1, wb2, Wt);
  k_build_w1b<<<(32 * 512) / tb, tb, 0, stream>>>(g1W, g1Wb);

  int rb = (N + 3) / 4;
  k_spmm1<<<rb, 256, 0, stream>>>(rp1, cols1, vals1, xb, nbb, N);

  int rowTiles = (N + 127) / 128;
  k_gemm1f<<<rowTiles * 4, 256, 0, stream>>>(xb, nbb, Wt, r1, headp, hinb, nrmsq, N);

  int pb = (N + 255) / 256;
  k_proj1<<<pb, 256, 0, stream>>>(hinb, g1Wb, h1, N);
  k_att1<<<rb, 256, 0, stream>>>(h1, g1a, nrmsq, a1s, a1d, nrm1, N);
  k_gat1<<<rb, 256, 0, stream>>>(rp2, dst2, h1, a1s, a1d, x1, N);
  k_spmm2<<<rb, 256, 0, stream>>>(rp1, cols1, vals1, x1, nb2, N);
  k_rel2<<<(N + tb - 1) / tb, tb, 0, stream>>>(x1, nb2, w2g1, w2g2, w2b1, w2b2, r2, W2, a2,
                                               headp, hg, a2s, a2d, nrm2, N);
  k_gat2<<<rb, 256, 0, stream>>>(rp2, dst2, hg, a2s, a2d, out, N);
}

// Round 4
// 2543.875 us; speedup vs baseline: 1.1992x; 1.0879x over previous
//
#include <hip/hip_runtime.h>
#include <stdint.h>

typedef __bf16 bf16;
typedef __bf16 bf16x8 __attribute__((ext_vector_type(8)));
typedef float  f32x4  __attribute__((ext_vector_type(4)));

#define LRELU_S 0.2f

__device__ __forceinline__ float lrelu(float v){ return v > 0.f ? v : LRELU_S * v; }
__device__ __forceinline__ float eluf(float v){ return v > 0.f ? v : expm1f(v); }

// ---------------- CSR build ----------------
__global__ void k_count(const int* __restrict__ adj, const int* __restrict__ selfe,
                        unsigned* __restrict__ cnt1, unsigned* __restrict__ cnt2, int E, int EN){
  int i = blockIdx.x * blockDim.x + threadIdx.x;
  if (i < E)  atomicAdd(&cnt1[adj[i]], 1u);
  if (i < EN) atomicAdd(&cnt2[selfe[i]], 1u);
}

__global__ void k_scan(unsigned* __restrict__ cnt, unsigned* __restrict__ rp, int n){
  __shared__ unsigned s[1024];
  int t = threadIdx.x;
  int chunk = (n + 1023) >> 10;
  int lo = t * chunk, hi = lo + chunk;
  if (lo > n) lo = n;
  if (hi > n) hi = n;
  unsigned sum = 0;
  for (int i = lo; i < hi; i++) sum += cnt[i];
  s[t] = sum; __syncthreads();
  for (int d = 1; d < 1024; d <<= 1){
    unsigned add = (t >= d) ? s[t - d] : 0u;
    __syncthreads();
    s[t] += add;
    __syncthreads();
  }
  unsigned run = s[t] - sum;
  for (int i = lo; i < hi; i++){ rp[i] = run; run += cnt[i]; cnt[i] = 0u; }
  if (hi == n) rp[n] = run;
}

__global__ void k_fill(const int* __restrict__ adj, const int* __restrict__ selfe,
                       const float* __restrict__ avals,
                       const unsigned* __restrict__ rp1, const unsigned* __restrict__ rp2,
                       unsigned* __restrict__ cur1, unsigned* __restrict__ cur2,
                       int* __restrict__ cols1, float* __restrict__ vals1,
                       int* __restrict__ dst2, int E, int EN){
  int i = blockIdx.x * blockDim.x + threadIdx.x;
  if (i < E){
    int r = adj[i];
    unsigned slot = rp1[r] + atomicAdd(&cur1[r], 1u);
    cols1[slot] = adj[E + i];
    vals1[slot] = avals[i];
  }
  if (i < EN){
    int sN = selfe[i];
    unsigned slot = rp2[sN] + atomicAdd(&cur2[sN], 1u);
    dst2[slot] = selfe[EN + i];
  }
}

// ---------------- conversions / packing ----------------
__global__ void k_cvt_x(const float* __restrict__ x, bf16* __restrict__ xb, int n8){
  int i = blockIdx.x * blockDim.x + threadIdx.x;
  if (i >= n8) return;
  const f32x4* p = (const f32x4*)(x + (size_t)i * 8);
  f32x4 a = p[0], b = p[1];
  bf16x8 o;
  o[0]=(bf16)a[0]; o[1]=(bf16)a[1]; o[2]=(bf16)a[2]; o[3]=(bf16)a[3];
  o[4]=(bf16)b[0]; o[5]=(bf16)b[1]; o[6]=(bf16)b[2]; o[7]=(bf16)b[3];
  *(bf16x8*)(xb + (size_t)i * 8) = o;
}

// Wt[c][k] = W[k][c], W = [[wg1, wb1],[wg2, wb2]] (cols 0..511 gamma, 512..1023 beta)
__global__ void k_build_wt(const float* __restrict__ wg1, const float* __restrict__ wg2,
                           const float* __restrict__ wb1, const float* __restrict__ wb2,
                           bf16* __restrict__ Wt){
  int i = blockIdx.x * blockDim.x + threadIdx.x;
  int c = i >> 10, k = i & 1023;
  float v;
  if (c < 512) v = (k < 512) ? wg1[k * 512 + c] : wg2[(k - 512) * 512 + c];
  else { int cc = c - 512; v = (k < 512) ? wb1[k * 512 + cc] : wb2[(k - 512) * 512 + cc]; }
  Wt[(size_t)c * 1024 + k] = (bf16)v;
}

// g1Wb[c][k] (bf16, c in 0..31): c = h*8+o -> g1W[h][k][o]; c>=24 -> 0
__global__ void k_build_w1b(const float* __restrict__ g1W, bf16* __restrict__ g1Wb){
  int i = blockIdx.x * blockDim.x + threadIdx.x;   // 32*512
  if (i >= 32 * 512) return;
  int c = i >> 9, k = i & 511;
  float v = 0.f;
  if (c < 24){ int h = c >> 3, o = c & 7; v = g1W[h * 4096 + k * 8 + o]; }
  g1Wb[i] = (bf16)v;
}

// ---------------- spmm layer 1: wave per row, 8 feats/lane, 4 gathers in flight ----------------
__global__ __launch_bounds__(256) void k_spmm1(const unsigned* __restrict__ rp, const int* __restrict__ cols,
    const float* __restrict__ vals, const bf16* __restrict__ xb, bf16* __restrict__ nbb, int N){
  int lane = threadIdx.x & 63;
  int r = blockIdx.x * 4 + (threadIdx.x >> 6);
  if (r >= N) return;
  unsigned b0 = rp[r], b1 = rp[r + 1];
  float acc[8] = {0.f,0.f,0.f,0.f,0.f,0.f,0.f,0.f};
  unsigned e = b0;
  for (; e + 4 <= b1; e += 4){
    int c0 = cols[e], c1 = cols[e+1], c2 = cols[e+2], c3 = cols[e+3];
    float v0 = vals[e], v1 = vals[e+1], v2 = vals[e+2], v3 = vals[e+3];
    bf16x8 x0 = *(const bf16x8*)(xb + (size_t)c0 * 512 + lane * 8);
    bf16x8 x1 = *(const bf16x8*)(xb + (size_t)c1 * 512 + lane * 8);
    bf16x8 x2 = *(const bf16x8*)(xb + (size_t)c2 * 512 + lane * 8);
    bf16x8 x3 = *(const bf16x8*)(xb + (size_t)c3 * 512 + lane * 8);
    #pragma unroll
    for (int j = 0; j < 8; j++)
      acc[j] += v0 * (float)x0[j] + v1 * (float)x1[j] + v2 * (float)x2[j] + v3 * (float)x3[j];
  }
  for (; e < b1; ++e){
    int c = cols[e]; float v = vals[e];
    bf16x8 xv = *(const bf16x8*)(xb + (size_t)c * 512 + lane * 8);
    #pragma unroll
    for (int j = 0; j < 8; j++) acc[j] += v * (float)xv[j];
  }
  bf16x8 o;
  #pragma unroll
  for (int j = 0; j < 8; j++) o[j] = (bf16)acc[j];
  *(bf16x8*)(nbb + (size_t)r * 512 + lane * 8) = o;
}

// ---------------- fused GEMM + relation1 epilogue (2-phase double-buffered) ----------------
// Block covers 128 rows x 128 features (gamma cols fBase.. AND beta cols 512+fBase..).
// K-loop: STAGE(kt+1) issued BEFORE compute(kt); single __syncthreads per tile
// (its implicit vmcnt(0)+lgkmcnt(0) drain covers the async DMA).
__global__ __launch_bounds__(256) void k_gemm1f(const bf16* __restrict__ xb, const bf16* __restrict__ nbb,
    const bf16* __restrict__ Wt, const float* __restrict__ r1, const int* __restrict__ headp,
    bf16* __restrict__ hinb, float* __restrict__ nrmsq, int M){
  __shared__ __align__(16) bf16 As[2][128 * 32];
  __shared__ __align__(16) bf16 Bg[2][128 * 32];
  __shared__ __align__(16) bf16 Bb[2][128 * 32];
  int bid = blockIdx.x;
  int chunk = gridDim.x >> 3;                     // nwg % 8 == 0
  int tile = (bid & 7) * chunk + (bid >> 3);      // XCD-chunked swizzle
  int rowBase = (tile >> 2) * 128;
  int fBase = (tile & 3) * 128;
  int tid = threadIdx.x, wave = tid >> 6, lane = tid & 63;
  int wm = wave >> 1, wn = wave & 1;
  f32x4 aG[4][4], aB[4][4];
  #pragma unroll
  for (int m = 0; m < 4; m++)
    #pragma unroll
    for (int n = 0; n < 4; n++){ aG[m][n] = (f32x4){0.f,0.f,0.f,0.f}; aB[m][n] = (f32x4){0.f,0.f,0.f,0.f}; }

  int sRow = wave * 16 + (lane >> 2);
  int sCol = (lane & 3) * 8;

  auto stage = [&](int buf, int kt){
    const bf16* Abase = (kt < 16) ? xb : nbb;
    int kcol = (kt & 15) * 32;
    #pragma unroll
    for (int c = 0; c < 2; c++){
      int rr = c * 64 + sRow;
      int grow = rowBase + rr; if (grow >= M) grow = M - 1;
      const bf16* asrc = Abase + (size_t)grow * 512 + kcol + sCol;
      __builtin_amdgcn_global_load_lds((const __attribute__((address_space(1))) void*)asrc,
          (__attribute__((address_space(3))) void*)&As[buf][(size_t)(c * 64 + wave * 16) * 32], 16, 0, 0);
      const bf16* gsrc = Wt + (size_t)(fBase + rr) * 1024 + kt * 32 + sCol;
      __builtin_amdgcn_global_load_lds((const __attribute__((address_space(1))) void*)gsrc,
          (__attribute__((address_space(3))) void*)&Bg[buf][(size_t)(c * 64 + wave * 16) * 32], 16, 0, 0);
      const bf16* bsrc = Wt + (size_t)(512 + fBase + rr) * 1024 + kt * 32 + sCol;
      __builtin_amdgcn_global_load_lds((const __attribute__((address_space(1))) void*)bsrc,
          (__attribute__((address_space(3))) void*)&Bb[buf][(size_t)(c * 64 + wave * 16) * 32], 16, 0, 0);
    }
  };

  stage(0, 0);
  __syncthreads();
  int cur = 0;
  for (int kt = 0; kt < 32; ++kt){
    if (kt + 1 < 32) stage(cur ^ 1, kt + 1);   // prefetch stays in flight during MFMA
    bf16x8 af[4], bg[4], bb[4];
    #pragma unroll
    for (int m = 0; m < 4; m++)
      af[m] = *(const bf16x8*)&As[cur][(wm * 64 + m * 16 + (lane & 15)) * 32 + (lane >> 4) * 8];
    #pragma unroll
    for (int n = 0; n < 4; n++){
      bg[n] = *(const bf16x8*)&Bg[cur][(wn * 64 + n * 16 + (lane & 15)) * 32 + (lane >> 4) * 8];
      bb[n] = *(const bf16x8*)&Bb[cur][(wn * 64 + n * 16 + (lane & 15)) * 32 + (lane >> 4) * 8];
    }
    #pragma unroll
    for (int m = 0; m < 4; m++)
      #pragma unroll
      for (int n = 0; n < 4; n++){
        aG[m][n] = __builtin_amdgcn_mfma_f32_16x16x32_bf16(af[m], bg[n], aG[m][n], 0, 0, 0);
        aB[m][n] = __builtin_amdgcn_mfma_f32_16x16x32_bf16(af[m], bb[n], aB[m][n], 0, 0, 0);
      }
    __syncthreads();
    cur ^= 1;
  }

  int head = *headp;
  float rf[4];
  #pragma unroll
  for (int n = 0; n < 4; n++) rf[n] = r1[fBase + wn * 64 + n * 16 + (lane & 15)];
  #pragma unroll
  for (int m = 0; m < 4; m++){
    #pragma unroll
    for (int j = 0; j < 4; j++){
      int row = rowBase + wm * 64 + m * 16 + (lane >> 4) * 4 + j;
      bool ok = row < M;
      int rowc = ok ? row : M - 1;
      float msq = 0.f;
      #pragma unroll
      for (int n = 0; n < 4; n++){
        int f = fBase + wn * 64 + n * 16 + (lane & 15);
        float g = lrelu(aG[m][n][j]);
        float b = lrelu(aB[m][n][j]);
        float xf = (float)xb[(size_t)rowc * 512 + f];
        float nf = (float)nbb[(size_t)rowc * 512 + f];
        float mv = xf + (g + 1.f) * rf[n] + b - nf;
        msq += mv * mv;
        float hin = head ? xf : (xf + mv);
        if (ok) hinb[(size_t)row * 512 + f] = (bf16)hin;
      }
      #pragma unroll
      for (int d = 1; d < 16; d <<= 1) msq += __shfl_xor(msq, d);
      if (ok && (lane & 15) == 0) atomicAdd(&nrmsq[row], msq);
    }
  }
}

// ---------------- skinny projection GEMM: hinb [N,512] @ g1Wb^T [512,32] -> h1 [N,32] f32 ----
__global__ __launch_bounds__(256) void k_proj1(const bf16* __restrict__ hinb, const bf16* __restrict__ g1Wb,
    float* __restrict__ h1, int N){
  __shared__ __align__(16) bf16 Bs[32 * 520];   // padded stride (2-way banks = free)
  __shared__ __align__(16) bf16 As[256 * 32];
  int tid = threadIdx.x, wave = tid >> 6, lane = tid & 63;
  #pragma unroll
  for (int i = 0; i < 8; i++){
    int e8 = tid + i * 256;
    int c = e8 >> 6, k = (e8 & 63) * 8;
    bf16x8 v = *(const bf16x8*)(g1Wb + c * 512 + k);
    *(bf16x8*)&Bs[c * 520 + k] = v;
  }
  int rBase = blockIdx.x * 256;
  f32x4 acc[4][2];
  #pragma unroll
  for (int m = 0; m < 4; m++){ acc[m][0] = (f32x4){0,0,0,0}; acc[m][1] = (f32x4){0,0,0,0}; }
  __syncthreads();
  for (int kt = 0; kt < 16; ++kt){
    #pragma unroll
    for (int i = 0; i < 4; i++){
      int r = (tid >> 2) + i * 64;
      int grow = rBase + r; if (grow >= N) grow = N - 1;
      const bf16* src = hinb + (size_t)grow * 512 + kt * 32 + (tid & 3) * 8;
      __builtin_amdgcn_global_load_lds((const __attribute__((address_space(1))) void*)src,
          (__attribute__((address_space(3))) void*)&As[(size_t)(i * 64 + wave * 16) * 32], 16, 0, 0);
    }
    __syncthreads();
    bf16x8 bf0 = *(const bf16x8*)&Bs[(0 * 16 + (lane & 15)) * 520 + kt * 32 + (lane >> 4) * 8];
    bf16x8 bf1 = *(const bf16x8*)&Bs[(1 * 16 + (lane & 15)) * 520 + kt * 32 + (lane >> 4) * 8];
    #pragma unroll
    for (int m = 0; m < 4; m++){
      bf16x8 af = *(const bf16x8*)&As[(wave * 64 + m * 16 + (lane & 15)) * 32 + (lane >> 4) * 8];
      acc[m][0] = __builtin_amdgcn_mfma_f32_16x16x32_bf16(af, bf0, acc[m][0], 0, 0, 0);
      acc[m][1] = __builtin_amdgcn_mfma_f32_16x16x32_bf16(af, bf1, acc[m][1], 0, 0, 0);
    }
    __syncthreads();
  }
  #pragma unroll
  for (int m = 0; m < 4; m++)
    #pragma unroll
    for (int n = 0; n < 2; n++)
      #pragma unroll
      for (int j = 0; j < 4; j++){
        int row = rBase + wave * 64 + m * 16 + (lane >> 4) * 4 + j;
        int col = n * 16 + (lane & 15);
        if (row < N) h1[(size_t)row * 32 + col] = acc[m][n][j];
      }
}

// ---------------- attn coeffs + nrm1: wave per row ----------------
__global__ __launch_bounds__(256) void k_att1(const float* __restrict__ h1, const float* __restrict__ g1a,
    const float* __restrict__ nrmsq, float* __restrict__ a1s, float* __restrict__ a1d,
    float* __restrict__ nrm1, int N){
  int lane = threadIdx.x & 63;
  int r = blockIdx.x * 4 + (threadIdx.x >> 6);
  if (r >= N) return;
  if (lane < 24){
    float hv = h1[(size_t)r * 32 + lane];
    int h = lane >> 3, o = lane & 7;
    float ps = hv * g1a[h * 16 + o];
    float pd = hv * g1a[h * 16 + 8 + o];
    #pragma unroll
    for (int d = 1; d < 8; d <<= 1){ ps += __shfl_xor(ps, d); pd += __shfl_xor(pd, d); }
    if (o == 0){ a1s[r * 4 + h] = ps; a1d[r * 4 + h] = pd; }
  } else if (lane == 24){
    nrm1[r] = sqrtf(nrmsq[r]);
  }
}

// ---------------- GAT layer 1 aggregation: wave per row (h1 stride 32) ----------------
__global__ __launch_bounds__(256) void k_gat1(const unsigned* __restrict__ rp2, const int* __restrict__ dst2,
    const float* __restrict__ h1, const float* __restrict__ a1s, const float* __restrict__ a1d,
    float* __restrict__ x1, int N){
  int lane = threadIdx.x & 63;
  int r = blockIdx.x * 4 + (threadIdx.x >> 6);
  if (r >= N) return;
  int cl = (lane < 24) ? lane : 0;
  int h = cl >> 3;
  float as = a1s[r * 4 + h];
  unsigned b0 = rp2[r], b1 = rp2[r + 1];
  float hp = 0.f, rs = 0.f;
  for (unsigned e = b0; e < b1; ++e){
    int d = dst2[e];
    float z = as + a1d[d * 4 + h];
    float ee = expf(-lrelu(z));
    hp += ee * h1[(size_t)d * 32 + cl];
    rs += ee;
  }
  if (lane < 24){
    float v = hp / rs;
    v = eluf(v); v = eluf(v);
    x1[(size_t)r * 24 + lane] = v;
  }
}

// ---------------- spmm layer 2: wave per row, 24 lanes ----------------
__global__ __launch_bounds__(256) void k_spmm2(const unsigned* __restrict__ rp, const int* __restrict__ cols,
    const float* __restrict__ vals, const float* __restrict__ x1, float* __restrict__ nb2, int N){
  int lane = threadIdx.x & 63;
  int r = blockIdx.x * 4 + (threadIdx.x >> 6);
  if (r >= N) return;
  int cl = (lane < 24) ? lane : 0;
  unsigned b0 = rp[r], b1 = rp[r + 1];
  float acc = 0.f;
  for (unsigned e = b0; e < b1; ++e)
    acc += vals[e] * x1[(size_t)cols[e] * 24 + cl];
  if (lane < 24) nb2[(size_t)r * 24 + lane] = acc;
}

// ---------------- relation2 + gat2_W projection + attn coeffs: thread per row ----------------
__global__ void k_rel2(const float* __restrict__ x1, const float* __restrict__ nb2,
    const float* __restrict__ wg1, const float* __restrict__ wg2,
    const float* __restrict__ wb1, const float* __restrict__ wb2,
    const float* __restrict__ r2, const float* __restrict__ W2, const float* __restrict__ a2,
    const int* __restrict__ headp,
    float* __restrict__ hg, float* __restrict__ a2s, float* __restrict__ a2d,
    float* __restrict__ nrm2, int N){
  int r = blockIdx.x * blockDim.x + threadIdx.x;
  if (r >= N) return;
  int head = *headp;
  float xr[24], nr[24], hin[24];
  #pragma unroll
  for (int i = 0; i < 24; i++){ xr[i] = x1[(size_t)r*24+i]; nr[i] = nb2[(size_t)r*24+i]; }
  float nrm = 0.f;
  #pragma unroll
  for (int j = 0; j < 24; j++){
    float gp = 0.f, bp = 0.f;
    #pragma unroll
    for (int i = 0; i < 24; i++){
      gp += xr[i] * wg1[i*24+j] + nr[i] * wg2[i*24+j];
      bp += xr[i] * wb1[i*24+j] + nr[i] * wb2[i*24+j];
    }
    float m = xr[j] + (lrelu(gp) + 1.f) * r2[j] + lrelu(bp) - nr[j];
    nrm += m * m;
    hin[j] = head ? xr[j] : (xr[j] + m);
  }
  nrm2[r] = sqrtf(nrm);
  float as = 0.f, ad = 0.f;
  #pragma unroll
  for (int c = 0; c < 32; c++){
    float v = 0.f;
    #pragma unroll
    for (int i = 0; i < 24; i++) v += hin[i] * W2[i*32+c];
    hg[(size_t)r*32 + c] = v;
    as += v * a2[c]; ad += v * a2[32 + c];
  }
  a2s[r] = as; a2d[r] = ad;
}

// ---------------- GAT layer 2 aggregation -> d_out ----------------
__global__ __launch_bounds__(256) void k_gat2(const unsigned* __restrict__ rp2, const int* __restrict__ dst2,
    const float* __restrict__ hg, const float* __restrict__ a2s, const float* __restrict__ a2d,
    float* __restrict__ out, int N){
  int lane = threadIdx.x & 63;
  int r = blockIdx.x * 4 + (threadIdx.x >> 6);
  if (r >= N) return;
  int cl = lane & 31;
  float as = a2s[r];
  unsigned b0 = rp2[r], b1 = rp2[r + 1];
  float hp = 0.f, rs = 0.f;
  for (unsigned e = b0; e < b1; ++e){
    int d = dst2[e];
    float z = as + a2d[d];
    float ee = expf(-lrelu(z));
    hp += ee * hg[(size_t)d * 32 + cl];
    rs += ee;
  }
  if (lane < 32) out[(size_t)r * 32 + lane] = eluf(hp / rs);
}

extern "C" void kernel_launch(void* const* d_in, const int* in_sizes, int n_in,
                              void* d_out, int out_size, void* d_ws, size_t ws_size,
                              hipStream_t stream){
  const float* x     = (const float*)d_in[0];
  const float* avals = (const float*)d_in[1];
  const float* wg1   = (const float*)d_in[2];
  const float* wg2   = (const float*)d_in[3];
  const float* wb1   = (const float*)d_in[4];
  const float* wb2   = (const float*)d_in[5];
  const float* r1    = (const float*)d_in[6];
  const float* g1W   = (const float*)d_in[7];
  const float* g1a   = (const float*)d_in[8];
  const float* w2g1  = (const float*)d_in[9];
  const float* w2g2  = (const float*)d_in[10];
  const float* w2b1  = (const float*)d_in[11];
  const float* w2b2  = (const float*)d_in[12];
  const float* r2    = (const float*)d_in[13];
  const float* W2    = (const float*)d_in[14];
  const float* a2    = (const float*)d_in[15];
  const int*   adj   = (const int*)d_in[16];
  const int*   selfe = (const int*)d_in[17];
  const int*   headp = (const int*)d_in[18];

  const int N  = in_sizes[0] / 512;
  const int E  = in_sizes[1];
  const int EN = in_sizes[17] / 2;

  char* w = (char*)d_ws; size_t off = 0;
  auto carve = [&](size_t bytes) -> char* {
    char* p = w + off; off = (off + bytes + 255) & ~(size_t)255; return p;
  };
  unsigned* rp1   = (unsigned*)carve(((size_t)N + 1) * 4);
  unsigned* rp2   = (unsigned*)carve(((size_t)N + 1) * 4);
  unsigned* cnt1  = (unsigned*)carve(((size_t)N + 1) * 4);
  unsigned* cnt2  = (unsigned*)carve(((size_t)N + 1) * 4);
  int*      cols1 = (int*)carve((size_t)E * 4);
  float*    vals1 = (float*)carve((size_t)E * 4);
  int*      dst2  = (int*)carve((size_t)EN * 4);
  bf16*     xb    = (bf16*)carve((size_t)N * 512 * 2);
  bf16*     nbb   = (bf16*)carve((size_t)N * 512 * 2);
  bf16*     Wt    = (bf16*)carve((size_t)1024 * 1024 * 2);
  bf16*     g1Wb  = (bf16*)carve((size_t)32 * 512 * 2);
  bf16*     hinb  = (bf16*)carve((size_t)N * 512 * 2);
  float*    nrmsq = (float*)carve((size_t)N * 4);
  float*    h1    = (float*)carve((size_t)N * 32 * 4);
  float*    a1s   = (float*)carve((size_t)N * 4 * 4);
  float*    a1d   = (float*)carve((size_t)N * 4 * 4);
  float*    x1    = (float*)carve((size_t)N * 24 * 4);
  float*    nb2   = (float*)carve((size_t)N * 24 * 4);
  float*    hg    = (float*)carve((size_t)N * 32 * 4);
  float*    a2s   = (float*)carve((size_t)N * 4);
  float*    a2d   = (float*)carve((size_t)N * 4);

  float* out  = (float*)d_out;
  float* nrm1 = out + (size_t)N * 32;
  float* nrm2 = nrm1 + N;

  hipMemsetAsync(cnt1, 0, ((size_t)N + 1) * 4, stream);
  hipMemsetAsync(cnt2, 0, ((size_t)N + 1) * 4, stream);
  hipMemsetAsync(nrmsq, 0, (size_t)N * 4, stream);

  const int tb = 256;
  k_count<<<(EN + tb - 1) / tb, tb, 0, stream>>>(adj, selfe, cnt1, cnt2, E, EN);
  k_scan<<<1, 1024, 0, stream>>>(cnt1, rp1, N);
  k_scan<<<1, 1024, 0, stream>>>(cnt2, rp2, N);
  k_fill<<<(EN + tb - 1) / tb, tb, 0, stream>>>(adj, selfe, avals, rp1, rp2, cnt1, cnt2,
                                                cols1, vals1, dst2, E, EN);
  int n8 = N * 512 / 8;
  k_cvt_x<<<(n8 + tb - 1) / tb, tb, 0, stream>>>(x, xb, n8);
  k_build_wt<<<(1024 * 1024) / tb, tb, 0, stream>>>(wg1, wg2, wb1, wb2, Wt);
  k_build_w1b<<<(32 * 512) / tb, tb, 0, stream>>>(g1W, g1Wb);

  int rb = (N + 3) / 4;
  k_spmm1<<<rb, 256, 0, stream>>>(rp1, cols1, vals1, xb, nbb, N);

  int rowTiles = (N + 127) / 128;
  k_gemm1f<<<rowTiles * 4, 256, 0, stream>>>(xb, nbb, Wt, r1, headp, hinb, nrmsq, N);

  int pb = (N + 255) / 256;
  k_proj1<<<pb, 256, 0, stream>>>(hinb, g1Wb, h1, N);
  k_att1<<<rb, 256, 0, stream>>>(h1, g1a, nrmsq, a1s, a1d, nrm1, N);
  k_gat1<<<rb, 256, 0, stream>>>(rp2, dst2, h1, a1s, a1d, x1, N);
  k_spmm2<<<rb, 256, 0, stream>>>(rp1, cols1, vals1, x1, nb2, N);
  k_rel2<<<(N + tb - 1) / tb, tb, 0, stream>>>(x1, nb2, w2g1, w2g2, w2b1, w2b2, r2, W2, a2,
                                               headp, hg, a2s, a2d, nrm2, N);
  k_gat2<<<rb, 256, 0, stream>>>(rp2, dst2, hg, a2s, a2d, out, N);
}

// Round 8
// 2357.556 us; speedup vs baseline: 1.2940x; 1.0790x over previous
//
#include <hip/hip_runtime.h>
#include <stdint.h>

typedef __bf16 bf16;
typedef __bf16 bf16x8 __attribute__((ext_vector_type(8)));
typedef float  f32x4  __attribute__((ext_vector_type(4)));

#define LRELU_S 0.2f

__device__ __forceinline__ float lrelu(float v){ return v > 0.f ? v : LRELU_S * v; }
__device__ __forceinline__ float eluf(float v){ return v > 0.f ? v : expm1f(v); }

// ---------------- CSR build ----------------
__global__ void k_count(const int* __restrict__ adj, const int* __restrict__ selfe,
                        unsigned* __restrict__ cnt1, unsigned* __restrict__ cnt2, int E, int EN){
  int i = blockIdx.x * blockDim.x + threadIdx.x;
  if (i < E)  atomicAdd(&cnt1[adj[i]], 1u);
  if (i < EN) atomicAdd(&cnt2[selfe[i]], 1u);
}

__global__ void k_scan(unsigned* __restrict__ cnt, unsigned* __restrict__ rp, int n){
  __shared__ unsigned s[1024];
  int t = threadIdx.x;
  int chunk = (n + 1023) >> 10;
  int lo = t * chunk, hi = lo + chunk;
  if (lo > n) lo = n;
  if (hi > n) hi = n;
  unsigned sum = 0;
  for (int i = lo; i < hi; i++) sum += cnt[i];
  s[t] = sum; __syncthreads();
  for (int d = 1; d < 1024; d <<= 1){
    unsigned add = (t >= d) ? s[t - d] : 0u;
    __syncthreads();
    s[t] += add;
    __syncthreads();
  }
  unsigned run = s[t] - sum;
  for (int i = lo; i < hi; i++){ rp[i] = run; run += cnt[i]; cnt[i] = 0u; }
  if (hi == n) rp[n] = run;
}

__global__ void k_fill(const int* __restrict__ adj, const int* __restrict__ selfe,
                       const float* __restrict__ avals,
                       const unsigned* __restrict__ rp1, const unsigned* __restrict__ rp2,
                       unsigned* __restrict__ cur1, unsigned* __restrict__ cur2,
                       int* __restrict__ cols1, float* __restrict__ vals1,
                       int* __restrict__ dst2, int E, int EN){
  int i = blockIdx.x * blockDim.x + threadIdx.x;
  if (i < E){
    int r = adj[i];
    unsigned slot = rp1[r] + atomicAdd(&cur1[r], 1u);
    cols1[slot] = adj[E + i];
    vals1[slot] = avals[i];
  }
  if (i < EN){
    int sN = selfe[i];
    unsigned slot = rp2[sN] + atomicAdd(&cur2[sN], 1u);
    dst2[slot] = selfe[EN + i];
  }
}

// ---------------- conversions / packing ----------------
__global__ void k_cvt_x(const float* __restrict__ x, bf16* __restrict__ xb, int n8){
  int i = blockIdx.x * blockDim.x + threadIdx.x;
  if (i >= n8) return;
  const f32x4* p = (const f32x4*)(x + (size_t)i * 8);
  f32x4 a = p[0], b = p[1];
  bf16x8 o;
  o[0]=(bf16)a[0]; o[1]=(bf16)a[1]; o[2]=(bf16)a[2]; o[3]=(bf16)a[3];
  o[4]=(bf16)b[0]; o[5]=(bf16)b[1]; o[6]=(bf16)b[2]; o[7]=(bf16)b[3];
  *(bf16x8*)(xb + (size_t)i * 8) = o;
}

// Wt[c][k] = W[k][c], W = [[wg1, wb1],[wg2, wb2]] (cols 0..511 gamma, 512..1023 beta)
__global__ void k_build_wt(const float* __restrict__ wg1, const float* __restrict__ wg2,
                           const float* __restrict__ wb1, const float* __restrict__ wb2,
                           bf16* __restrict__ Wt){
  int i = blockIdx.x * blockDim.x + threadIdx.x;
  int c = i >> 10, k = i & 1023;
  float v;
  if (c < 512) v = (k < 512) ? wg1[k * 512 + c] : wg2[(k - 512) * 512 + c];
  else { int cc = c - 512; v = (k < 512) ? wb1[k * 512 + cc] : wb2[(k - 512) * 512 + cc]; }
  Wt[(size_t)c * 1024 + k] = (bf16)v;
}

// g1Wb[c][k] (bf16, c in 0..31): c = h*8+o -> g1W[h][k][o]; c>=24 -> 0
__global__ void k_build_w1b(const float* __restrict__ g1W, bf16* __restrict__ g1Wb){
  int i = blockIdx.x * blockDim.x + threadIdx.x;   // 32*512
  if (i >= 32 * 512) return;
  int c = i >> 9, k = i & 511;
  float v = 0.f;
  if (c < 24){ int h = c >> 3, o = c & 7; v = g1W[h * 4096 + k * 8 + o]; }
  g1Wb[i] = (bf16)v;
}

// ---------------- spmm layer 1: wave per row, 8 feats/lane, 4 gathers in flight ----------------
__global__ __launch_bounds__(256) void k_spmm1(const unsigned* __restrict__ rp, const int* __restrict__ cols,
    const float* __restrict__ vals, const bf16* __restrict__ xb, bf16* __restrict__ nbb, int N){
  int lane = threadIdx.x & 63;
  int r = blockIdx.x * 4 + (threadIdx.x >> 6);
  if (r >= N) return;
  unsigned b0 = rp[r], b1 = rp[r + 1];
  float acc[8] = {0.f,0.f,0.f,0.f,0.f,0.f,0.f,0.f};
  unsigned e = b0;
  for (; e + 4 <= b1; e += 4){
    int c0 = cols[e], c1 = cols[e+1], c2 = cols[e+2], c3 = cols[e+3];
    float v0 = vals[e], v1 = vals[e+1], v2 = vals[e+2], v3 = vals[e+3];
    bf16x8 x0 = *(const bf16x8*)(xb + (size_t)c0 * 512 + lane * 8);
    bf16x8 x1 = *(const bf16x8*)(xb + (size_t)c1 * 512 + lane * 8);
    bf16x8 x2 = *(const bf16x8*)(xb + (size_t)c2 * 512 + lane * 8);
    bf16x8 x3 = *(const bf16x8*)(xb + (size_t)c3 * 512 + lane * 8);
    #pragma unroll
    for (int j = 0; j < 8; j++)
      acc[j] += v0 * (float)x0[j] + v1 * (float)x1[j] + v2 * (float)x2[j] + v3 * (float)x3[j];
  }
  for (; e < b1; ++e){
    int c = cols[e]; float v = vals[e];
    bf16x8 xv = *(const bf16x8*)(xb + (size_t)c * 512 + lane * 8);
    #pragma unroll
    for (int j = 0; j < 8; j++) acc[j] += v * (float)xv[j];
  }
  bf16x8 o;
  #pragma unroll
  for (int j = 0; j < 8; j++) o[j] = (bf16)acc[j];
  *(bf16x8*)(nbb + (size_t)r * 512 + lane * 8) = o;
}

// ---------------- fused GEMM + relation1 epilogue (2-phase dbuf + bank-conflict swizzle) ----
// LDS dest linear (global_load_lds requirement); global SOURCE col-slot pre-permuted by
// slot ^= (row>>1)&3 within each 32-col slice; fragment READ applies the same XOR (rule #21).
__global__ __launch_bounds__(256) void k_gemm1f(const bf16* __restrict__ xb, const bf16* __restrict__ nbb,
    const bf16* __restrict__ Wt, const float* __restrict__ r1, const int* __restrict__ headp,
    bf16* __restrict__ hinb, float* __restrict__ nrmsq, int M){
  __shared__ __align__(16) bf16 As[2][128 * 32];
  __shared__ __align__(16) bf16 Bg[2][128 * 32];
  __shared__ __align__(16) bf16 Bb[2][128 * 32];
  int bid = blockIdx.x;
  int chunk = gridDim.x >> 3;                     // nwg % 8 == 0
  int tile = (bid & 7) * chunk + (bid >> 3);      // XCD-chunked swizzle
  int rowBase = (tile >> 2) * 128;
  int fBase = (tile & 3) * 128;
  int tid = threadIdx.x, wave = tid >> 6, lane = tid & 63;
  int wm = wave >> 1, wn = wave & 1;
  f32x4 aG[4][4], aB[4][4];
  #pragma unroll
  for (int m = 0; m < 4; m++)
    #pragma unroll
    for (int n = 0; n < 4; n++){ aG[m][n] = (f32x4){0.f,0.f,0.f,0.f}; aB[m][n] = (f32x4){0.f,0.f,0.f,0.f}; }

  int sRow = wave * 16 + (lane >> 2);
  // source col-slot permuted so that linear LDS write lands data at its swizzled slot
  int sColSwz = (((lane & 3) ^ ((lane >> 3) & 3))) * 8;

  auto stage = [&](int buf, int kt){
    const bf16* Abase = (kt < 16) ? xb : nbb;
    int kcol = (kt & 15) * 32;
    #pragma unroll
    for (int c = 0; c < 2; c++){
      int rr = c * 64 + sRow;
      int grow = rowBase + rr; if (grow >= M) grow = M - 1;
      const bf16* asrc = Abase + (size_t)grow * 512 + kcol + sColSwz;
      __builtin_amdgcn_global_load_lds((const __attribute__((address_space(1))) void*)asrc,
          (__attribute__((address_space(3))) void*)&As[buf][(size_t)(c * 64 + wave * 16) * 32], 16, 0, 0);
      const bf16* gsrc = Wt + (size_t)(fBase + rr) * 1024 + kt * 32 + sColSwz;
      __builtin_amdgcn_global_load_lds((const __attribute__((address_space(1))) void*)gsrc,
          (__attribute__((address_space(3))) void*)&Bg[buf][(size_t)(c * 64 + wave * 16) * 32], 16, 0, 0);
      const bf16* bsrc = Wt + (size_t)(512 + fBase + rr) * 1024 + kt * 32 + sColSwz;
      __builtin_amdgcn_global_load_lds((const __attribute__((address_space(1))) void*)bsrc,
          (__attribute__((address_space(3))) void*)&Bb[buf][(size_t)(c * 64 + wave * 16) * 32], 16, 0, 0);
    }
  };

  stage(0, 0);
  __syncthreads();
  int cur = 0;
  int fr = lane & 15;
  int sRead = (((lane >> 4) ^ ((fr >> 1) & 3))) * 8;   // same XOR as source permutation
  for (int kt = 0; kt < 32; ++kt){
    if (kt + 1 < 32) stage(cur ^ 1, kt + 1);   // prefetch stays in flight during MFMA
    bf16x8 af[4], bg[4], bb[4];
    #pragma unroll
    for (int m = 0; m < 4; m++)
      af[m] = *(const bf16x8*)&As[cur][(wm * 64 + m * 16 + fr) * 32 + sRead];
    #pragma unroll
    for (int n = 0; n < 4; n++){
      bg[n] = *(const bf16x8*)&Bg[cur][(wn * 64 + n * 16 + fr) * 32 + sRead];
      bb[n] = *(const bf16x8*)&Bb[cur][(wn * 64 + n * 16 + fr) * 32 + sRead];
    }
    #pragma unroll
    for (int m = 0; m < 4; m++)
      #pragma unroll
      for (int n = 0; n < 4; n++){
        aG[m][n] = __builtin_amdgcn_mfma_f32_16x16x32_bf16(af[m], bg[n], aG[m][n], 0, 0, 0);
        aB[m][n] = __builtin_amdgcn_mfma_f32_16x16x32_bf16(af[m], bb[n], aB[m][n], 0, 0, 0);
      }
    __syncthreads();
    cur ^= 1;
  }

  int head = *headp;
  float rf[4];
  #pragma unroll
  for (int n = 0; n < 4; n++) rf[n] = r1[fBase + wn * 64 + n * 16 + (lane & 15)];
  #pragma unroll
  for (int m = 0; m < 4; m++){
    #pragma unroll
    for (int j = 0; j < 4; j++){
      int row = rowBase + wm * 64 + m * 16 + (lane >> 4) * 4 + j;
      bool ok = row < M;
      int rowc = ok ? row : M - 1;
      float msq = 0.f;
      #pragma unroll
      for (int n = 0; n < 4; n++){
        int f = fBase + wn * 64 + n * 16 + (lane & 15);
        float g = lrelu(aG[m][n][j]);
        float b = lrelu(aB[m][n][j]);
        float xf = (float)xb[(size_t)rowc * 512 + f];
        float nf = (float)nbb[(size_t)rowc * 512 + f];
        float mv = xf + (g + 1.f) * rf[n] + b - nf;
        msq += mv * mv;
        float hin = head ? xf : (xf + mv);
        if (ok) hinb[(size_t)row * 512 + f] = (bf16)hin;
      }
      #pragma unroll
      for (int d = 1; d < 16; d <<= 1) msq += __shfl_xor(msq, d);
      if (ok && (lane & 15) == 0) atomicAdd(&nrmsq[row], msq);
    }
  }
}

// ---------------- skinny projection GEMM: hinb [N,512] @ g1Wb^T [512,32] -> h1 [N,32] f32 ----
__global__ __launch_bounds__(256) void k_proj1(const bf16* __restrict__ hinb, const bf16* __restrict__ g1Wb,
    float* __restrict__ h1, int N){
  __shared__ __align__(16) bf16 Bs[32 * 520];   // padded stride (2-way banks = free)
  __shared__ __align__(16) bf16 As[256 * 32];
  int tid = threadIdx.x, wave = tid >> 6, lane = tid & 63;
  #pragma unroll
  for (int i = 0; i < 8; i++){
    int e8 = tid + i * 256;
    int c = e8 >> 6, k = (e8 & 63) * 8;
    bf16x8 v = *(const bf16x8*)(g1Wb + c * 512 + k);
    *(bf16x8*)&Bs[c * 520 + k] = v;
  }
  int rBase = blockIdx.x * 256;
  f32x4 acc[4][2];
  #pragma unroll
  for (int m = 0; m < 4; m++){ acc[m][0] = (f32x4){0,0,0,0}; acc[m][1] = (f32x4){0,0,0,0}; }
  __syncthreads();
  for (int kt = 0; kt < 16; ++kt){
    #pragma unroll
    for (int i = 0; i < 4; i++){
      int r = (tid >> 2) + i * 64;
      int grow = rBase + r; if (grow >= N) grow = N - 1;
      const bf16* src = hinb + (size_t)grow * 512 + kt * 32 + (tid & 3) * 8;
      __builtin_amdgcn_global_load_lds((const __attribute__((address_space(1))) void*)src,
          (__attribute__((address_space(3))) void*)&As[(size_t)(i * 64 + wave * 16) * 32], 16, 0, 0);
    }
    __syncthreads();
    bf16x8 bf0 = *(const bf16x8*)&Bs[(0 * 16 + (lane & 15)) * 520 + kt * 32 + (lane >> 4) * 8];
    bf16x8 bf1 = *(const bf16x8*)&Bs[(1 * 16 + (lane & 15)) * 520 + kt * 32 + (lane >> 4) * 8];
    #pragma unroll
    for (int m = 0; m < 4; m++){
      bf16x8 af = *(const bf16x8*)&As[(wave * 64 + m * 16 + (lane & 15)) * 32 + (lane >> 4) * 8];
      acc[m][0] = __builtin_amdgcn_mfma_f32_16x16x32_bf16(af, bf0, acc[m][0], 0, 0, 0);
      acc[m][1] = __builtin_amdgcn_mfma_f32_16x16x32_bf16(af, bf1, acc[m][1], 0, 0, 0);
    }
    __syncthreads();
  }
  #pragma unroll
  for (int m = 0; m < 4; m++)
    #pragma unroll
    for (int n = 0; n < 2; n++)
      #pragma unroll
      for (int j = 0; j < 4; j++){
        int row = rBase + wave * 64 + m * 16 + (lane >> 4) * 4 + j;
        int col = n * 16 + (lane & 15);
        if (row < N) h1[(size_t)row * 32 + col] = acc[m][n][j];
      }
}

// ---------------- attn coeffs + nrm1: wave per row ----------------
__global__ __launch_bounds__(256) void k_att1(const float* __restrict__ h1, const float* __restrict__ g1a,
    const float* __restrict__ nrmsq, float* __restrict__ a1s, float* __restrict__ a1d,
    float* __restrict__ nrm1, int N){
  int lane = threadIdx.x & 63;
  int r = blockIdx.x * 4 + (threadIdx.x >> 6);
  if (r >= N) return;
  if (lane < 24){
    float hv = h1[(size_t)r * 32 + lane];
    int h = lane >> 3, o = lane & 7;
    float ps = hv * g1a[h * 16 + o];
    float pd = hv * g1a[h * 16 + 8 + o];
    #pragma unroll
    for (int d = 1; d < 8; d <<= 1){ ps += __shfl_xor(ps, d); pd += __shfl_xor(pd, d); }
    if (o == 0){ a1s[r * 4 + h] = ps; a1d[r * 4 + h] = pd; }
  } else if (lane == 24){
    nrm1[r] = sqrtf(nrmsq[r]);
  }
}

// ---------------- GAT layer 1 aggregation: 2 rows per wave (32-lane halves) ----------------
__global__ __launch_bounds__(256) void k_gat1(const unsigned* __restrict__ rp2, const int* __restrict__ dst2,
    const float* __restrict__ h1, const float* __restrict__ a1s, const float* __restrict__ a1d,
    float* __restrict__ x1, int N){
  int lane = threadIdx.x & 63;
  int r = blockIdx.x * 8 + (threadIdx.x >> 6) * 2 + (lane >> 5);
  if (r >= N) return;
  int l2 = lane & 31;
  int cl = (l2 < 24) ? l2 : 0;
  int h = cl >> 3;
  float as = a1s[r * 4 + h];
  unsigned b0 = rp2[r], b1 = rp2[r + 1];
  float hp = 0.f, rs = 0.f;
  for (unsigned e = b0; e < b1; ++e){
    int d = dst2[e];
    float z = as + a1d[d * 4 + h];
    float ee = expf(-lrelu(z));
    hp += ee * h1[(size_t)d * 32 + cl];
    rs += ee;
  }
  if (l2 < 24){
    float v = hp / rs;
    v = eluf(v); v = eluf(v);
    x1[(size_t)r * 24 + l2] = v;
  }
}

// ---------------- spmm layer 2: 2 rows per wave ----------------
__global__ __launch_bounds__(256) void k_spmm2(const unsigned* __restrict__ rp, const int* __restrict__ cols,
    const float* __restrict__ vals, const float* __restrict__ x1, float* __restrict__ nb2, int N){
  int lane = threadIdx.x & 63;
  int r = blockIdx.x * 8 + (threadIdx.x >> 6) * 2 + (lane >> 5);
  if (r >= N) return;
  int l2 = lane & 31;
  int cl = (l2 < 24) ? l2 : 0;
  unsigned b0 = rp[r], b1 = rp[r + 1];
  float acc = 0.f;
  for (unsigned e = b0; e < b1; ++e)
    acc += vals[e] * x1[(size_t)cols[e] * 24 + cl];
  if (l2 < 24) nb2[(size_t)r * 24 + l2] = acc;
}

// ---------------- relation2 + gat2_W projection + attn coeffs: thread per row ----------------
__global__ void k_rel2(const float* __restrict__ x1, const float* __restrict__ nb2,
    const float* __restrict__ wg1, const float* __restrict__ wg2,
    const float* __restrict__ wb1, const float* __restrict__ wb2,
    const float* __restrict__ r2, const float* __restrict__ W2, const float* __restrict__ a2,
    const int* __restrict__ headp,
    float* __restrict__ hg, float* __restrict__ a2s, float* __restrict__ a2d,
    float* __restrict__ nrm2, int N){
  int r = blockIdx.x * blockDim.x + threadIdx.x;
  if (r >= N) return;
  int head = *headp;
  float xr[24], nr[24], hin[24];
  #pragma unroll
  for (int i = 0; i < 24; i++){ xr[i] = x1[(size_t)r*24+i]; nr[i] = nb2[(size_t)r*24+i]; }
  float nrm = 0.f;
  #pragma unroll
  for (int j = 0; j < 24; j++){
    float gp = 0.f, bp = 0.f;
    #pragma unroll
    for (int i = 0; i < 24; i++){
      gp += xr[i] * wg1[i*24+j] + nr[i] * wg2[i*24+j];
      bp += xr[i] * wb1[i*24+j] + nr[i] * wb2[i*24+j];
    }
    float m = xr[j] + (lrelu(gp) + 1.f) * r2[j] + lrelu(bp) - nr[j];
    nrm += m * m;
    hin[j] = head ? xr[j] : (xr[j] + m);
  }
  nrm2[r] = sqrtf(nrm);
  float as = 0.f, ad = 0.f;
  #pragma unroll
  for (int c = 0; c < 32; c++){
    float v = 0.f;
    #pragma unroll
    for (int i = 0; i < 24; i++) v += hin[i] * W2[i*32+c];
    hg[(size_t)r*32 + c] = v;
    as += v * a2[c]; ad += v * a2[32 + c];
  }
  a2s[r] = as; a2d[r] = ad;
}

// ---------------- GAT layer 2 aggregation -> d_out: 2 rows per wave ----------------
__global__ __launch_bounds__(256) void k_gat2(const unsigned* __restrict__ rp2, const int* __restrict__ dst2,
    const float* __restrict__ hg, const float* __restrict__ a2s, const float* __restrict__ a2d,
    float* __restrict__ out, int N){
  int lane = threadIdx.x & 63;
  int r = blockIdx.x * 8 + (threadIdx.x >> 6) * 2 + (lane >> 5);
  if (r >= N) return;
  int cl = lane & 31;
  float as = a2s[r];
  unsigned b0 = rp2[r], b1 = rp2[r + 1];
  float hp = 0.f, rs = 0.f;
  for (unsigned e = b0; e < b1; ++e){
    int d = dst2[e];
    float z = as + a2d[d];
    float ee = expf(-lrelu(z));
    hp += ee * hg[(size_t)d * 32 + cl];
    rs += ee;
  }
  out[(size_t)r * 32 + cl] = eluf(hp / rs);
}

extern "C" void kernel_launch(void* const* d_in, const int* in_sizes, int n_in,
                              void* d_out, int out_size, void* d_ws, size_t ws_size,
                              hipStream_t stream){
  const float* x     = (const float*)d_in[0];
  const float* avals = (const float*)d_in[1];
  const float* wg1   = (const float*)d_in[2];
  const float* wg2   = (const float*)d_in[3];
  const float* wb1   = (const float*)d_in[4];
  const float* wb2   = (const float*)d_in[5];
  const float* r1    = (const float*)d_in[6];
  const float* g1W   = (const float*)d_in[7];
  const float* g1a   = (const float*)d_in[8];
  const float* w2g1  = (const float*)d_in[9];
  const float* w2g2  = (const float*)d_in[10];
  const float* w2b1  = (const float*)d_in[11];
  const float* w2b2  = (const float*)d_in[12];
  const float* r2    = (const float*)d_in[13];
  const float* W2    = (const float*)d_in[14];
  const float* a2    = (const float*)d_in[15];
  const int*   adj   = (const int*)d_in[16];
  const int*   selfe = (const int*)d_in[17];
  const int*   headp = (const int*)d_in[18];

  const int N  = in_sizes[0] / 512;
  const int E  = in_sizes[1];
  const int EN = in_sizes[17] / 2;

  char* w = (char*)d_ws; size_t off = 0;
  auto carve = [&](size_t bytes) -> char* {
    char* p = w + off; off = (off + bytes + 255) & ~(size_t)255; return p;
  };
  unsigned* rp1   = (unsigned*)carve(((size_t)N + 1) * 4);
  unsigned* rp2   = (unsigned*)carve(((size_t)N + 1) * 4);
  unsigned* cnt1  = (unsigned*)carve(((size_t)N + 1) * 4);
  unsigned* cnt2  = (unsigned*)carve(((size_t)N + 1) * 4);
  int*      cols1 = (int*)carve((size_t)E * 4);
  float*    vals1 = (float*)carve((size_t)E * 4);
  int*      dst2  = (int*)carve((size_t)EN * 4);
  bf16*     xb    = (bf16*)carve((size_t)N * 512 * 2);
  bf16*     nbb   = (bf16*)carve((size_t)N * 512 * 2);
  bf16*     Wt    = (bf16*)carve((size_t)1024 * 1024 * 2);
  bf16*     g1Wb  = (bf16*)carve((size_t)32 * 512 * 2);
  bf16*     hinb  = (bf16*)carve((size_t)N * 512 * 2);
  float*    nrmsq = (float*)carve((size_t)N * 4);
  float*    h1    = (float*)carve((size_t)N * 32 * 4);
  float*    a1s   = (float*)carve((size_t)N * 4 * 4);
  float*    a1d   = (float*)carve((size_t)N * 4 * 4);
  float*    x1    = (float*)carve((size_t)N * 24 * 4);
  float*    nb2   = (float*)carve((size_t)N * 24 * 4);
  float*    hg    = (float*)carve((size_t)N * 32 * 4);
  float*    a2s   = (float*)carve((size_t)N * 4);
  float*    a2d   = (float*)carve((size_t)N * 4);

  float* out  = (float*)d_out;
  float* nrm1 = out + (size_t)N * 32;
  float* nrm2 = nrm1 + N;

  hipMemsetAsync(cnt1, 0, ((size_t)N + 1) * 4, stream);
  hipMemsetAsync(cnt2, 0, ((size_t)N + 1) * 4, stream);
  hipMemsetAsync(nrmsq, 0, (size_t)N * 4, stream);

  const int tb = 256;
  k_count<<<(EN + tb - 1) / tb, tb, 0, stream>>>(adj, selfe, cnt1, cnt2, E, EN);
  k_scan<<<1, 1024, 0, stream>>>(cnt1, rp1, N);
  k_scan<<<1, 1024, 0, stream>>>(cnt2, rp2, N);
  k_fill<<<(EN + tb - 1) / tb, tb, 0, stream>>>(adj, selfe, avals, rp1, rp2, cnt1, cnt2,
                                                cols1, vals1, dst2, E, EN);
  int n8 = N * 512 / 8;
  k_cvt_x<<<(n8 + tb - 1) / tb, tb, 0, stream>>>(x, xb, n8);
  k_build_wt<<<(1024 * 1024) / tb, tb, 0, stream>>>(wg1, wg2, wb1, wb2, Wt);
  k_build_w1b<<<(32 * 512) / tb, tb, 0, stream>>>(g1W, g1Wb);

  int rb = (N + 3) / 4;
  int rb8 = (N + 7) / 8;
  k_spmm1<<<rb, 256, 0, stream>>>(rp1, cols1, vals1, xb, nbb, N);

  int rowTiles = (N + 127) / 128;
  k_gemm1f<<<rowTiles * 4, 256, 0, stream>>>(xb, nbb, Wt, r1, headp, hinb, nrmsq, N);

  int pb = (N + 255) / 256;
  k_proj1<<<pb, 256, 0, stream>>>(hinb, g1Wb, h1, N);
  k_att1<<<rb, 256, 0, stream>>>(h1, g1a, nrmsq, a1s, a1d, nrm1, N);
  k_gat1<<<rb8, 256, 0, stream>>>(rp2, dst2, h1, a1s, a1d, x1, N);
  k_spmm2<<<rb8, 256, 0, stream>>>(rp1, cols1, vals1, x1, nb2, N);
  k_rel2<<<(N + tb - 1) / tb, tb, 0, stream>>>(x1, nb2, w2g1, w2g2, w2b1, w2b2, r2, W2, a2,
                                               headp, hg, a2s, a2d, nrm2, N);
  k_gat2<<<rb8, 256, 0, stream>>>(rp2, dst2, hg, a2s, a2d, out, N);
}